// Round 16
// baseline (266.657 us; speedup 1.0000x reference)
//
#include <hip/hip_runtime.h>
#include <hip/hip_bf16.h>
#include <math.h>

#define NPX   65536          // 256*256
#define IMGST 4194304        // 64*65536
#define NB    4

// ================= K1 merged: depthwise conv (x,y) + pooled Grams ============
// Grid (1344, 8). x<1280: dwconv (XCD-chunked, balanced k-classes).
// x>=1280: poolgram block (irow = (x-1280)*2 + (y>>2), b = y&3) — independent
// of dwconv (reads x,y only), Ppart lives in ws so no conflict with yh=d_out.
template<int K, int RT>
__device__ __forceinline__ void dw_strip(const float* __restrict__ in,
                                         const float* __restrict__ wp,
                                         float* __restrict__ outp,
                                         int rowS, int c4) {
    float w[K * K];
#pragma unroll
    for (int i = 0; i < K * K; ++i) w[i] = wp[i];   // block-uniform -> s_load

    float acc[RT][4];
#pragma unroll
    for (int i = 0; i < RT; ++i)
#pragma unroll
        for (int j = 0; j < 4; ++j) acc[i][j] = 0.f;

    const bool lok = (c4 != 0);
    const bool rok = (c4 < 252);
    const int off0 = lok ? -4 : 0;
    const int off2 = rok ? 4 : 0;

#pragma unroll
    for (int ri = 0; ri < RT + K - 1; ++ri) {
        const int gr = rowS - K / 2 + ri;   // wave-uniform row index
        float v[12];
        if ((unsigned)gr < 256u) {
            const float* rp = in + gr * 256 + c4;
            const float4 m0 = *reinterpret_cast<const float4*>(rp + off0);
            const float4 m1 = *reinterpret_cast<const float4*>(rp);
            const float4 m2 = *reinterpret_cast<const float4*>(rp + off2);
            v[0] = lok ? m0.x : 0.f; v[1] = lok ? m0.y : 0.f;
            v[2] = lok ? m0.z : 0.f; v[3] = lok ? m0.w : 0.f;
            v[4] = m1.x; v[5] = m1.y; v[6] = m1.z; v[7] = m1.w;
            v[8] = rok ? m2.x : 0.f;  v[9] = rok ? m2.y : 0.f;
            v[10] = rok ? m2.z : 0.f; v[11] = rok ? m2.w : 0.f;
        } else {
#pragma unroll
            for (int t = 0; t < 12; ++t) v[t] = 0.f;
        }
#pragma unroll
        for (int i = 0; i < RT; ++i) {
            const int dy = ri - i;
            if (dy >= 0 && dy < K) {
#pragma unroll
                for (int dx = 0; dx < K; ++dx) {
                    const float wv = w[dy * K + dx];
#pragma unroll
                    for (int j = 0; j < 4; ++j)
                        acc[i][j] = fmaf(wv, v[j + dx + 4 - K / 2], acc[i][j]);
                }
            }
        }
    }

    float* obase = outp + (size_t)rowS * 256 + c4;
#pragma unroll
    for (int i = 0; i < RT; ++i) {
        float4 o;
        o.x = acc[i][0]; o.y = acc[i][1]; o.z = acc[i][2]; o.w = acc[i][3];
        *reinterpret_cast<float4*>(obase + i * 256) = o;
    }
}

__device__ __forceinline__ void poolgram_body(
        const float* __restrict__ x, const float* __restrict__ y,
        float* __restrict__ Ppart, int irow, int b, int tid) {
    __shared__ float sx[64 * 65];
    __shared__ float sy[64 * 65];
    const int rt = tid >> 4, ct = tid & 15;
    float aXY[16], aXX[16], aYY[16];
#pragma unroll
    for (int i = 0; i < 16; ++i) { aXY[i] = 0.f; aXX[i] = 0.f; aYY[i] = 0.f; }
    const size_t ibase = (size_t)b * IMGST + (size_t)(2 * irow) * 256;

    for (int tile = 0; tile < 2; ++tile) {
        __syncthreads();
        for (int idx = tid; idx < 4096; idx += 256) {
            const int c = idx >> 6, jj = idx & 63;
            const size_t g = ibase + (size_t)c * NPX + 2 * (tile * 64 + jj);
            const float2 a0 = *reinterpret_cast<const float2*>(x + g);
            const float2 a1 = *reinterpret_cast<const float2*>(x + g + 256);
            const float2 b0 = *reinterpret_cast<const float2*>(y + g);
            const float2 b1 = *reinterpret_cast<const float2*>(y + g + 256);
            sx[jj * 65 + c] = 0.25f * (a0.x + a0.y + a1.x + a1.y);
            sy[jj * 65 + c] = 0.25f * (b0.x + b0.y + b1.x + b1.y);
        }
        __syncthreads();
        for (int p = 0; p < 64; ++p) {
            float xr[4], xc[4], yr[4], yc[4];
#pragma unroll
            for (int j = 0; j < 4; ++j) {
                xr[j] = sx[p * 65 + rt * 4 + j];
                xc[j] = sx[p * 65 + ct * 4 + j];
                yr[j] = sy[p * 65 + rt * 4 + j];
                yc[j] = sy[p * 65 + ct * 4 + j];
            }
#pragma unroll
            for (int r = 0; r < 4; ++r)
#pragma unroll
                for (int c2 = 0; c2 < 4; ++c2) {
                    aXY[r * 4 + c2] = fmaf(xr[r], yc[c2], aXY[r * 4 + c2]);
                    aXX[r * 4 + c2] = fmaf(xr[r], xc[c2], aXX[r * 4 + c2]);
                    aYY[r * 4 + c2] = fmaf(yr[r], yc[c2], aYY[r * 4 + c2]);
                }
        }
    }
    float* outp = Ppart + ((size_t)b * 128 + irow) * 12288;
#pragma unroll
    for (int r = 0; r < 4; ++r)
#pragma unroll
        for (int c2 = 0; c2 < 4; ++c2) {
            const int o = (rt * 4 + r) * 64 + ct * 4 + c2;
            outp[o]        = aXY[r * 4 + c2];
            outp[4096 + o] = aXX[r * 4 + c2];
            outp[8192 + o] = aYY[r * 4 + c2];
        }
}

__global__ __launch_bounds__(256) void dsattn_dwpool(
        const float* __restrict__ xin, const float* __restrict__ yin,
        float* __restrict__ xout, float* __restrict__ yout,
        const float* __restrict__ x3, const float* __restrict__ x5,
        const float* __restrict__ x7, const float* __restrict__ y3,
        const float* __restrict__ y5, const float* __restrict__ y7,
        float* __restrict__ Ppart) {
    const int tid = threadIdx.x;
    const int xb = blockIdx.x;

    if (xb >= 1280) {   // -------- poolgram blocks --------
        const int irow = (xb - 1280) * 2 + (blockIdx.y >> 2);
        const int b = blockIdx.y & 3;
        poolgram_body(xin, yin, Ppart, irow, b, tid);
        return;
    }

    // -------- dwconv blocks --------
    const int xcd = xb & 7;
    const int v   = xb >> 3;
    const int sel = blockIdx.y >> 2;
    const int b   = blockIdx.y & 3;
    const int tc = tid & 63, tr = tid >> 6;   // wave-uniform tr
    const int c4 = tc * 4;

    const float* inb = (sel == 0 ? xin : yin) + (size_t)b * IMGST;
    float* outb      = (sel == 0 ? xout : yout) + (size_t)b * IMGST;

    if (v < 64) {                 // k7 (longest) first
        const int idx = xcd * 64 + v;
        const int c = 48 + (idx >> 5), band = idx & 31;
        const float* w = (sel == 0 ? x7 : y7) + (c - 48) * 49;
        dw_strip<7, 2>(inb + (size_t)c * NPX, w, outb + (size_t)c * NPX,
                       band * 8 + tr * 2, c4);
    } else if (v < 128) {         // k3
        const int idx = xcd * 64 + (v - 64);
        const int c = idx >> 4, band = idx & 15;
        const float* w = (sel == 0 ? x3 : y3) + c * 9;
        dw_strip<3, 4>(inb + (size_t)c * NPX, w, outb + (size_t)c * NPX,
                       band * 16 + tr * 4, c4);
    } else {                      // k5
        const int idx = xcd * 32 + (v - 128);
        const int c = 32 + (idx >> 4), band = idx & 15;
        const float* w = (sel == 0 ? x5 : y5) + (c - 32) * 25;
        dw_strip<5, 4>(inb + (size_t)c * NPX, w, outb + (size_t)c * NPX,
                       band * 16 + tr * 4, c4);
    }
}

// ================= K2: cross-Gram S_b = xh @ yh^T, K-split partials =================
__global__ __launch_bounds__(256) void dsattn_crossgram(
        const float* __restrict__ xh, const float* __restrict__ yh,
        float* __restrict__ Spart) {
    __shared__ float sx[64 * 65];
    __shared__ float sy[64 * 65];
    const int tid = threadIdx.x;
    const int chunk = blockIdx.x;
    const int b = blockIdx.y;
    const int rt = tid >> 4;      // 0..15
    const int ct = tid & 15;      // 0..15
    float acc[16];
#pragma unroll
    for (int i = 0; i < 16; ++i) acc[i] = 0.f;
    const size_t ibase = (size_t)b * IMGST + chunk * 512;

    for (int tile = 0; tile < 8; ++tile) {
        __syncthreads();
        for (int idx = tid; idx < 1024; idx += 256) {
            const int c = idx >> 4, p4 = (idx & 15) * 4;
            const size_t g = ibase + (size_t)c * NPX + tile * 64 + p4;
            const float4 vx = *reinterpret_cast<const float4*>(&xh[g]);
            const float4 vy = *reinterpret_cast<const float4*>(&yh[g]);
            sx[(p4 + 0) * 65 + c] = vx.x; sx[(p4 + 1) * 65 + c] = vx.y;
            sx[(p4 + 2) * 65 + c] = vx.z; sx[(p4 + 3) * 65 + c] = vx.w;
            sy[(p4 + 0) * 65 + c] = vy.x; sy[(p4 + 1) * 65 + c] = vy.y;
            sy[(p4 + 2) * 65 + c] = vy.z; sy[(p4 + 3) * 65 + c] = vy.w;
        }
        __syncthreads();
        for (int p = 0; p < 64; ++p) {
            float xr[4], yc[4];
#pragma unroll
            for (int j = 0; j < 4; ++j) {
                xr[j] = sx[p * 65 + rt * 4 + j];
                yc[j] = sy[p * 65 + ct * 4 + j];
            }
#pragma unroll
            for (int r = 0; r < 4; ++r)
#pragma unroll
                for (int c2 = 0; c2 < 4; ++c2)
                    acc[r * 4 + c2] = fmaf(xr[r], yc[c2], acc[r * 4 + c2]);
        }
    }
    float* outp = Spart + ((size_t)b * 128 + chunk) * 4096;
#pragma unroll
    for (int r = 0; r < 4; ++r)
#pragma unroll
        for (int c2 = 0; c2 < 4; ++c2)
            outp[(rt * 4 + r) * 64 + ct * 4 + c2] = acc[r * 4 + c2];
}

// ================= K2b: merged reduce (Spart -> Sred, Ppart -> Pred) ==========
// grid (64, 4): x<16 -> S (i = x*256+tid, 0..4095), x>=16 -> P (i = (x-16)*256+tid)
__global__ __launch_bounds__(256) void dsattn_reduceSP(
        const float* __restrict__ Spart, float* __restrict__ Sred,
        const float* __restrict__ Ppart, float* __restrict__ Pred) {
    const int b = blockIdx.y;
    if (blockIdx.x < 16) {
        const int i = blockIdx.x * 256 + threadIdx.x;
        const float* p = Spart + (size_t)b * 128 * 4096 + i;
        float s = 0.f;
#pragma unroll 4
        for (int k = 0; k < 128; ++k) s += p[(size_t)k * 4096];
        Sred[b * 4096 + i] = s;
    } else {
        const int i = (blockIdx.x - 16) * 256 + threadIdx.x;
        const float* p = Ppart + (size_t)b * 128 * 12288 + i;
        float s = 0.f;
#pragma unroll 4
        for (int k = 0; k < 128; ++k) s += p[(size_t)k * 12288];
        Pred[b * 12288 + i] = s;
    }
}

// ================= K_A: sandwich products, grid (4 units, 4 img) =================
__global__ __launch_bounds__(256) void dsattn_sandwich(
        const float* __restrict__ Pred, const float* __restrict__ Sred,
        const float* __restrict__ wql, const float* __restrict__ wkl,
        const float* __restrict__ wq,  const float* __restrict__ wk,
        float* __restrict__ nq2g, float* __restrict__ nk2g,
        float* __restrict__ Gg, float* __restrict__ pooledg) {
    __shared__ float Wl[64 * 65];
    __shared__ float Sl[64 * 65];
    __shared__ float Tl[64 * 65];
    __shared__ float red[256];
    const int unit = blockIdx.x, b = blockIdx.y, tid = threadIdx.x;
    const float *W1, *W2, *Sg;
    if (unit == 0)      { W1 = wql; W2 = wql; Sg = Pred + (size_t)b * 12288 + 4096; }
    else if (unit == 1) { W1 = wkl; W2 = wkl; Sg = Pred + (size_t)b * 12288 + 8192; }
    else if (unit == 2) { W1 = wql; W2 = wkl; Sg = Pred + (size_t)b * 12288; }
    else                { W1 = wq;  W2 = wk;  Sg = Sred + (size_t)b * 4096; }

    for (int i = tid; i < 4096; i += 256) {
        const int r = i >> 6, c = i & 63;
        Wl[r * 65 + c] = W1[i];
        Sl[r * 65 + c] = Sg[i];
    }
    __syncthreads();

    const int rt = tid >> 4, ct = tid & 15;
    float acc[16];
#pragma unroll
    for (int i = 0; i < 16; ++i) acc[i] = 0.f;
    for (int cc = 0; cc < 64; ++cc) {
        float wr[4], sc[4];
#pragma unroll
        for (int j = 0; j < 4; ++j) {
            wr[j] = Wl[(rt * 4 + j) * 65 + cc];
            sc[j] = Sl[cc * 65 + ct * 4 + j];
        }
#pragma unroll
        for (int r = 0; r < 4; ++r)
#pragma unroll
            for (int c2 = 0; c2 < 4; ++c2)
                acc[r * 4 + c2] = fmaf(wr[r], sc[c2], acc[r * 4 + c2]);
    }
#pragma unroll
    for (int r = 0; r < 4; ++r)
#pragma unroll
        for (int c2 = 0; c2 < 4; ++c2)
            Tl[(rt * 4 + r) * 65 + ct * 4 + c2] = acc[r * 4 + c2];
    __syncthreads();
    for (int i = tid; i < 4096; i += 256) Sl[(i >> 6) * 65 + (i & 63)] = W2[i];
    __syncthreads();

    if (unit == 2) {
        for (int i = tid; i < 512; i += 256) {
            const int h = i >> 6, r = (i >> 3) & 7, d = i & 7;
            float s = 0.f;
#pragma unroll
            for (int c = 0; c < 64; ++c)
                s = fmaf(Tl[(h * 8 + r) * 65 + c], Sl[(h * 8 + d) * 65 + c], s);
            Gg[b * 512 + i] = s;
        }
    } else {
        const int r = tid >> 2, part = tid & 3;
        float s = 0.f;
#pragma unroll
        for (int q = 0; q < 16; ++q) {
            const int cp = part * 16 + q;
            s = fmaf(Tl[r * 65 + cp], Sl[r * 65 + cp], s);
        }
        red[tid] = s;
        __syncthreads();
        if (tid < 64) {
            const float v = red[tid * 4] + red[tid * 4 + 1] + red[tid * 4 + 2] + red[tid * 4 + 3];
            if (unit == 0)      nq2g[b * 64 + tid] = v;
            else if (unit == 1) nk2g[b * 64 + tid] = v;
            else                pooledg[b * 64 + tid] = v * (1.f / 65536.f);
        }
    }
}

// ================= K_B: MLP + softmax + tvl, grid 4 =================
__global__ __launch_bounds__(256) void dsattn_smallmid(
        const float* __restrict__ nq2g, const float* __restrict__ nk2g,
        const float* __restrict__ Gg, const float* __restrict__ pooledg,
        const float* __restrict__ temp, const float* __restrict__ w1,
        const float* __restrict__ w2, const float* __restrict__ wvl,
        float* __restrict__ hattg, float* __restrict__ tvlg) {
    __shared__ float att[512];
    __shared__ float z[16];
    const int b = blockIdx.x, tid = threadIdx.x;
    if (tid < 16) {
        float a = 0.f;
#pragma unroll
        for (int c = 0; c < 64; ++c) a = fmaf(w1[tid * 64 + c], pooledg[b * 64 + c], a);
        z[tid] = fmaxf(a, 0.f);
    }
    if (tid < 64) {
        const int h = tid >> 3;
        const float tpr = temp[h];
        const float nq = fmaxf(sqrtf(nq2g[b * 64 + tid]), 1e-12f);
        float a[8], m = -1e30f;
#pragma unroll
        for (int d = 0; d < 8; ++d) {
            const float nk = fmaxf(sqrtf(nk2g[b * 64 + h * 8 + d]), 1e-12f);
            a[d] = Gg[b * 512 + tid * 8 + d] / (nq * nk) * tpr;
            m = fmaxf(m, a[d]);
        }
        float ssum = 0.f;
#pragma unroll
        for (int d = 0; d < 8; ++d) { a[d] = expf(a[d] - m); ssum += a[d]; }
        const float inv = 1.f / ssum;
#pragma unroll
        for (int d = 0; d < 8; ++d) att[tid * 8 + d] = a[d] * inv;
    }
    __syncthreads();
    if (tid < 64) {
        float a = 0.f;
#pragma unroll
        for (int i = 0; i < 16; ++i) a = fmaf(w2[tid * 16 + i], z[i], a);
        hattg[b * 64 + tid] = tanhf(a);
    }
    for (int i = tid; i < 4096; i += 256) {
        const int m = i >> 6, c = i & 63, h = m >> 3;
        float s = 0.f;
#pragma unroll
        for (int d = 0; d < 8; ++d) s = fmaf(att[m * 8 + d], wvl[(h * 8 + d) * 64 + c], s);
        tvlg[b * 4096 + i] = s;
    }
}

// ================= K_C: fold -> At, Bt; grid (2 units, 4 img) =================
__global__ __launch_bounds__(256) void dsattn_fold(
        const float* __restrict__ wproj, const float* __restrict__ wvh,
        const float* __restrict__ hattg, const float* __restrict__ tvlg,
        float* __restrict__ At, float* __restrict__ Bt) {
    __shared__ float Pl[64 * 65];   // [o][m]
    __shared__ float Vl[64 * 65];   // [m][c]
    __shared__ float hm[64];
    const int unit = blockIdx.x, b = blockIdx.y, tid = threadIdx.x;
    if (tid < 64) hm[tid] = hattg[b * 64 + tid];
    for (int i = tid; i < 4096; i += 256) Pl[(i >> 6) * 65 + (i & 63)] = wproj[i];
    __syncthreads();
    for (int i = tid; i < 4096; i += 256) {
        const int m = i >> 6, c = i & 63;
        Vl[m * 65 + c] = (unit == 0) ? hm[m] * wvh[i] : tvlg[b * 4096 + i];
    }
    __syncthreads();

    const int rt = tid >> 4, ct = tid & 15;  // rt: c rows, ct: o cols
    float acc[16];
#pragma unroll
    for (int i = 0; i < 16; ++i) acc[i] = 0.f;
    for (int m = 0; m < 64; ++m) {
        float pv[4], vv[4];
#pragma unroll
        for (int j = 0; j < 4; ++j) {
            pv[j] = Pl[(ct * 4 + j) * 65 + m];
            vv[j] = Vl[m * 65 + rt * 4 + j];
        }
#pragma unroll
        for (int r = 0; r < 4; ++r)
#pragma unroll
            for (int c2 = 0; c2 < 4; ++c2)
                acc[r * 4 + c2] = fmaf(pv[c2], vv[r], acc[r * 4 + c2]);
    }
    float* outp = ((unit == 0) ? At : Bt) + (size_t)b * 4096;
#pragma unroll
    for (int r = 0; r < 4; ++r)
#pragma unroll
        for (int c2 = 0; c2 < 4; ++c2)
            outp[(rt * 4 + r) * 64 + ct * 4 + c2] = acc[r * 4 + c2];
}

// ================= K6: out = A_b @ xh + B_b @ y  (SGPR A/B, no LDS) =================
__global__ __launch_bounds__(256, 4) void dsattn_final(
        const float* __restrict__ xh, const float* __restrict__ y,
        const float* __restrict__ At, const float* __restrict__ Bt,
        float* __restrict__ out) {
    const int tid = threadIdx.x;
    const int b = blockIdx.y;
    const int lane = tid & 63;
    const int oc0 = __builtin_amdgcn_readfirstlane((tid >> 6) * 16);  // wave-uniform
    const size_t base = (size_t)b * IMGST + (size_t)blockIdx.x * 256 + lane * 4;
    const float* __restrict__ Ab = At + b * 4096 + oc0;
    const float* __restrict__ Bb = Bt + b * 4096 + oc0;

    float acc[16][4];
#pragma unroll
    for (int j = 0; j < 16; ++j)
#pragma unroll
        for (int k = 0; k < 4; ++k) acc[j][k] = 0.f;

#pragma unroll 2
    for (int c = 0; c < 64; ++c) {
        const float4 xv = *reinterpret_cast<const float4*>(xh + base + (size_t)c * NPX);
        const float4 yv = *reinterpret_cast<const float4*>(y  + base + (size_t)c * NPX);
#pragma unroll
        for (int j = 0; j < 16; ++j) {
            const float a  = Ab[c * 64 + j];   // uniform -> s_load
            const float bb = Bb[c * 64 + j];   // uniform -> s_load
            acc[j][0] = fmaf(a, xv.x, acc[j][0]);
            acc[j][1] = fmaf(a, xv.y, acc[j][1]);
            acc[j][2] = fmaf(a, xv.z, acc[j][2]);
            acc[j][3] = fmaf(a, xv.w, acc[j][3]);
            acc[j][0] = fmaf(bb, yv.x, acc[j][0]);
            acc[j][1] = fmaf(bb, yv.y, acc[j][1]);
            acc[j][2] = fmaf(bb, yv.z, acc[j][2]);
            acc[j][3] = fmaf(bb, yv.w, acc[j][3]);
        }
    }

    float* op = out + base;
#pragma unroll
    for (int j = 0; j < 16; ++j) {
        float4 v;
        v.x = acc[j][0]; v.y = acc[j][1]; v.z = acc[j][2]; v.w = acc[j][3];
        *reinterpret_cast<float4*>(op + (size_t)(oc0 + j) * NPX) = v;
    }
}

// ================= launch =================
extern "C" void kernel_launch(void* const* d_in, const int* in_sizes, int n_in,
                              void* d_out, int out_size, void* d_ws, size_t ws_size,
                              hipStream_t stream) {
    const float* x      = (const float*)d_in[0];
    const float* y      = (const float*)d_in[1];
    const float* hp1_w3 = (const float*)d_in[2];
    const float* hp1_w5 = (const float*)d_in[3];
    const float* hp1_w7 = (const float*)d_in[4];
    const float* hp2_w3 = (const float*)d_in[5];
    const float* hp2_w5 = (const float*)d_in[6];
    const float* hp2_w7 = (const float*)d_in[7];
    const float* qh_w   = (const float*)d_in[8];
    const float* kh_w   = (const float*)d_in[9];
    const float* vh_w   = (const float*)d_in[10];
    const float* ql_w   = (const float*)d_in[11];
    const float* kl_w   = (const float*)d_in[12];
    const float* vl_w   = (const float*)d_in[13];
    const float* proj_w = (const float*)d_in[14];
    const float* attn_w1 = (const float*)d_in[15];
    const float* attn_w2 = (const float*)d_in[16];
    const float* temperature = (const float*)d_in[17];

    float* out = (float*)d_out;

    // ws layout (floats); capacity >= 109.5 MB proven in round 15.
    float* xh     = (float*)d_ws;                    // 16,777,216
    float* Spart  = xh + (size_t)NB * IMGST;         // 2,097,152
    float* Sred   = Spart + (size_t)4 * 128 * 4096;  // 16,384
    float* Pred   = Sred + 16384;                    // 49,152
    float* nq2    = Pred + 49152;                    // 256
    float* nk2    = nq2 + 256;                       // 256
    float* G      = nk2 + 256;                       // 2,048
    float* pooled = G + 2048;                        // 256
    float* hatt   = pooled + 256;                    // 256
    float* tvl    = hatt + 256;                      // 16,384
    float* At     = tvl + 16384;                     // 16,384
    float* Bt     = At + 16384;                      // 16,384
    float* Ppart  = Bt + 16384;                      // 6,291,456 (ends ~101 MB)

    float* yh = out;   // d_out scratch: written by dwconv part, read by crossgram,
                       // overwritten only by dsattn_final at the end.

    dsattn_dwpool<<<dim3(1344, 8), 256, 0, stream>>>(x, y, xh, yh,
                                                     hp1_w3, hp1_w5, hp1_w7,
                                                     hp2_w3, hp2_w5, hp2_w7,
                                                     Ppart);
    dsattn_crossgram<<<dim3(128, 4), 256, 0, stream>>>(xh, yh, Spart);
    dsattn_reduceSP<<<dim3(64, 4), 256, 0, stream>>>(Spart, Sred, Ppart, Pred);
    dsattn_sandwich<<<dim3(4, 4), 256, 0, stream>>>(Pred, Sred, ql_w, kl_w, qh_w, kh_w,
                                                    nq2, nk2, G, pooled);
    dsattn_smallmid<<<4, 256, 0, stream>>>(nq2, nk2, G, pooled, temperature,
                                           attn_w1, attn_w2, vl_w, hatt, tvl);
    dsattn_fold<<<dim3(2, 4), 256, 0, stream>>>(proj_w, vh_w, hatt, tvl, At, Bt);
    dsattn_final<<<dim3(256, 4), 256, 0, stream>>>(xh, y, At, Bt, out);
}

// Round 17
// 266.343 us; speedup vs baseline: 1.0012x; 1.0012x over previous
//
#include <hip/hip_runtime.h>
#include <hip/hip_bf16.h>
#include <math.h>

#define NPX   65536          // 256*256
#define IMGST 4194304        // 64*65536
#define NB    4

// ================= K1: depthwise conv (round-14 version, standalone) =========
template<int K, int RT>
__device__ __forceinline__ void dw_strip(const float* __restrict__ in,
                                         const float* __restrict__ wp,
                                         float* __restrict__ outp,
                                         int rowS, int c4) {
    float w[K * K];
#pragma unroll
    for (int i = 0; i < K * K; ++i) w[i] = wp[i];   // block-uniform -> s_load

    float acc[RT][4];
#pragma unroll
    for (int i = 0; i < RT; ++i)
#pragma unroll
        for (int j = 0; j < 4; ++j) acc[i][j] = 0.f;

    const bool lok = (c4 != 0);
    const bool rok = (c4 < 252);
    const int off0 = lok ? -4 : 0;
    const int off2 = rok ? 4 : 0;

#pragma unroll
    for (int ri = 0; ri < RT + K - 1; ++ri) {
        const int gr = rowS - K / 2 + ri;   // wave-uniform row index
        float v[12];
        if ((unsigned)gr < 256u) {
            const float* rp = in + gr * 256 + c4;
            const float4 m0 = *reinterpret_cast<const float4*>(rp + off0);
            const float4 m1 = *reinterpret_cast<const float4*>(rp);
            const float4 m2 = *reinterpret_cast<const float4*>(rp + off2);
            v[0] = lok ? m0.x : 0.f; v[1] = lok ? m0.y : 0.f;
            v[2] = lok ? m0.z : 0.f; v[3] = lok ? m0.w : 0.f;
            v[4] = m1.x; v[5] = m1.y; v[6] = m1.z; v[7] = m1.w;
            v[8] = rok ? m2.x : 0.f;  v[9] = rok ? m2.y : 0.f;
            v[10] = rok ? m2.z : 0.f; v[11] = rok ? m2.w : 0.f;
        } else {
#pragma unroll
            for (int t = 0; t < 12; ++t) v[t] = 0.f;
        }
#pragma unroll
        for (int i = 0; i < RT; ++i) {
            const int dy = ri - i;
            if (dy >= 0 && dy < K) {
#pragma unroll
                for (int dx = 0; dx < K; ++dx) {
                    const float wv = w[dy * K + dx];
#pragma unroll
                    for (int j = 0; j < 4; ++j)
                        acc[i][j] = fmaf(wv, v[j + dx + 4 - K / 2], acc[i][j]);
                }
            }
        }
    }

    float* obase = outp + (size_t)rowS * 256 + c4;
#pragma unroll
    for (int i = 0; i < RT; ++i) {
        float4 o;
        o.x = acc[i][0]; o.y = acc[i][1]; o.z = acc[i][2]; o.w = acc[i][3];
        *reinterpret_cast<float4*>(obase + i * 256) = o;
    }
}

__global__ __launch_bounds__(256) void dsattn_dwconv2(
        const float* __restrict__ xin, const float* __restrict__ yin,
        float* __restrict__ xout, float* __restrict__ yout,
        const float* __restrict__ x3, const float* __restrict__ x5,
        const float* __restrict__ x7, const float* __restrict__ y3,
        const float* __restrict__ y5, const float* __restrict__ y7) {
    const int tid = threadIdx.x;
    const int xcd = blockIdx.x & 7;
    const int v   = blockIdx.x >> 3;
    const int sel = blockIdx.y >> 2;
    const int b   = blockIdx.y & 3;
    const int tc = tid & 63, tr = tid >> 6;   // wave-uniform tr
    const int c4 = tc * 4;

    const float* inb = (sel == 0 ? xin : yin) + (size_t)b * IMGST;
    float* outb      = (sel == 0 ? xout : yout) + (size_t)b * IMGST;

    if (v < 64) {                 // k7 (longest) first
        const int idx = xcd * 64 + v;
        const int c = 48 + (idx >> 5), band = idx & 31;
        const float* w = (sel == 0 ? x7 : y7) + (c - 48) * 49;
        dw_strip<7, 2>(inb + (size_t)c * NPX, w, outb + (size_t)c * NPX,
                       band * 8 + tr * 2, c4);
    } else if (v < 128) {         // k3
        const int idx = xcd * 64 + (v - 64);
        const int c = idx >> 4, band = idx & 15;
        const float* w = (sel == 0 ? x3 : y3) + c * 9;
        dw_strip<3, 4>(inb + (size_t)c * NPX, w, outb + (size_t)c * NPX,
                       band * 16 + tr * 4, c4);
    } else {                      // k5
        const int idx = xcd * 32 + (v - 128);
        const int c = 32 + (idx >> 4), band = idx & 15;
        const float* w = (sel == 0 ? x5 : y5) + (c - 32) * 25;
        dw_strip<5, 4>(inb + (size_t)c * NPX, w, outb + (size_t)c * NPX,
                       band * 16 + tr * 4, c4);
    }
}

// ================= K2 merged: crossgram + poolgram (matching footprints) ======
// grid (256, 4): x<128 -> poolgram row x; x>=128 -> crossgram chunk x-128.
// Shared LDS buffers passed into both bodies (33 KB total, same as standalone).
__device__ __forceinline__ void poolgram_body(
        float* sx, float* sy,
        const float* __restrict__ x, const float* __restrict__ y,
        float* __restrict__ Ppart, int irow, int b, int tid) {
    const int rt = tid >> 4, ct = tid & 15;
    float aXY[16], aXX[16], aYY[16];
#pragma unroll
    for (int i = 0; i < 16; ++i) { aXY[i] = 0.f; aXX[i] = 0.f; aYY[i] = 0.f; }
    const size_t ibase = (size_t)b * IMGST + (size_t)(2 * irow) * 256;

    for (int tile = 0; tile < 2; ++tile) {
        __syncthreads();
        for (int idx = tid; idx < 4096; idx += 256) {
            const int c = idx >> 6, jj = idx & 63;
            const size_t g = ibase + (size_t)c * NPX + 2 * (tile * 64 + jj);
            const float2 a0 = *reinterpret_cast<const float2*>(x + g);
            const float2 a1 = *reinterpret_cast<const float2*>(x + g + 256);
            const float2 b0 = *reinterpret_cast<const float2*>(y + g);
            const float2 b1 = *reinterpret_cast<const float2*>(y + g + 256);
            sx[jj * 65 + c] = 0.25f * (a0.x + a0.y + a1.x + a1.y);
            sy[jj * 65 + c] = 0.25f * (b0.x + b0.y + b1.x + b1.y);
        }
        __syncthreads();
        for (int p = 0; p < 64; ++p) {
            float xr[4], xc[4], yr[4], yc[4];
#pragma unroll
            for (int j = 0; j < 4; ++j) {
                xr[j] = sx[p * 65 + rt * 4 + j];
                xc[j] = sx[p * 65 + ct * 4 + j];
                yr[j] = sy[p * 65 + rt * 4 + j];
                yc[j] = sy[p * 65 + ct * 4 + j];
            }
#pragma unroll
            for (int r = 0; r < 4; ++r)
#pragma unroll
                for (int c2 = 0; c2 < 4; ++c2) {
                    aXY[r * 4 + c2] = fmaf(xr[r], yc[c2], aXY[r * 4 + c2]);
                    aXX[r * 4 + c2] = fmaf(xr[r], xc[c2], aXX[r * 4 + c2]);
                    aYY[r * 4 + c2] = fmaf(yr[r], yc[c2], aYY[r * 4 + c2]);
                }
        }
    }
    float* outp = Ppart + ((size_t)b * 128 + irow) * 12288;
#pragma unroll
    for (int r = 0; r < 4; ++r)
#pragma unroll
        for (int c2 = 0; c2 < 4; ++c2) {
            const int o = (rt * 4 + r) * 64 + ct * 4 + c2;
            outp[o]        = aXY[r * 4 + c2];
            outp[4096 + o] = aXX[r * 4 + c2];
            outp[8192 + o] = aYY[r * 4 + c2];
        }
}

__device__ __forceinline__ void crossgram_body(
        float* sx, float* sy,
        const float* __restrict__ xh, const float* __restrict__ yh,
        float* __restrict__ Spart, int chunk, int b, int tid) {
    const int rt = tid >> 4, ct = tid & 15;
    float acc[16];
#pragma unroll
    for (int i = 0; i < 16; ++i) acc[i] = 0.f;
    const size_t ibase = (size_t)b * IMGST + chunk * 512;

    for (int tile = 0; tile < 8; ++tile) {
        __syncthreads();
        for (int idx = tid; idx < 1024; idx += 256) {
            const int c = idx >> 4, p4 = (idx & 15) * 4;
            const size_t g = ibase + (size_t)c * NPX + tile * 64 + p4;
            const float4 vx = *reinterpret_cast<const float4*>(&xh[g]);
            const float4 vy = *reinterpret_cast<const float4*>(&yh[g]);
            sx[(p4 + 0) * 65 + c] = vx.x; sx[(p4 + 1) * 65 + c] = vx.y;
            sx[(p4 + 2) * 65 + c] = vx.z; sx[(p4 + 3) * 65 + c] = vx.w;
            sy[(p4 + 0) * 65 + c] = vy.x; sy[(p4 + 1) * 65 + c] = vy.y;
            sy[(p4 + 2) * 65 + c] = vy.z; sy[(p4 + 3) * 65 + c] = vy.w;
        }
        __syncthreads();
        for (int p = 0; p < 64; ++p) {
            float xr[4], yc[4];
#pragma unroll
            for (int j = 0; j < 4; ++j) {
                xr[j] = sx[p * 65 + rt * 4 + j];
                yc[j] = sy[p * 65 + ct * 4 + j];
            }
#pragma unroll
            for (int r = 0; r < 4; ++r)
#pragma unroll
                for (int c2 = 0; c2 < 4; ++c2)
                    acc[r * 4 + c2] = fmaf(xr[r], yc[c2], acc[r * 4 + c2]);
        }
    }
    float* outp = Spart + ((size_t)b * 128 + chunk) * 4096;
#pragma unroll
    for (int r = 0; r < 4; ++r)
#pragma unroll
        for (int c2 = 0; c2 < 4; ++c2)
            outp[(rt * 4 + r) * 64 + ct * 4 + c2] = acc[r * 4 + c2];
}

__global__ __launch_bounds__(256) void dsattn_grams(
        const float* __restrict__ x, const float* __restrict__ y,
        const float* __restrict__ xh, const float* __restrict__ yh,
        float* __restrict__ Spart, float* __restrict__ Ppart) {
    __shared__ float sx[64 * 65];
    __shared__ float sy[64 * 65];
    const int tid = threadIdx.x;
    const int b = blockIdx.y;
    if (blockIdx.x < 128)
        poolgram_body(sx, sy, x, y, Ppart, blockIdx.x, b, tid);
    else
        crossgram_body(sx, sy, xh, yh, Spart, blockIdx.x - 128, b, tid);
}

// ================= K2b: merged reduce (Spart -> Sred, Ppart -> Pred) ==========
__global__ __launch_bounds__(256) void dsattn_reduceSP(
        const float* __restrict__ Spart, float* __restrict__ Sred,
        const float* __restrict__ Ppart, float* __restrict__ Pred) {
    const int b = blockIdx.y;
    if (blockIdx.x < 16) {
        const int i = blockIdx.x * 256 + threadIdx.x;
        const float* p = Spart + (size_t)b * 128 * 4096 + i;
        float s = 0.f;
#pragma unroll 4
        for (int k = 0; k < 128; ++k) s += p[(size_t)k * 4096];
        Sred[b * 4096 + i] = s;
    } else {
        const int i = (blockIdx.x - 16) * 256 + threadIdx.x;
        const float* p = Ppart + (size_t)b * 128 * 12288 + i;
        float s = 0.f;
#pragma unroll 4
        for (int k = 0; k < 128; ++k) s += p[(size_t)k * 12288];
        Pred[b * 12288 + i] = s;
    }
}

// ================= K_A: sandwich products, grid (4 units, 4 img) =================
__global__ __launch_bounds__(256) void dsattn_sandwich(
        const float* __restrict__ Pred, const float* __restrict__ Sred,
        const float* __restrict__ wql, const float* __restrict__ wkl,
        const float* __restrict__ wq,  const float* __restrict__ wk,
        float* __restrict__ nq2g, float* __restrict__ nk2g,
        float* __restrict__ Gg, float* __restrict__ pooledg) {
    __shared__ float Wl[64 * 65];
    __shared__ float Sl[64 * 65];
    __shared__ float Tl[64 * 65];
    __shared__ float red[256];
    const int unit = blockIdx.x, b = blockIdx.y, tid = threadIdx.x;
    const float *W1, *W2, *Sg;
    if (unit == 0)      { W1 = wql; W2 = wql; Sg = Pred + (size_t)b * 12288 + 4096; }
    else if (unit == 1) { W1 = wkl; W2 = wkl; Sg = Pred + (size_t)b * 12288 + 8192; }
    else if (unit == 2) { W1 = wql; W2 = wkl; Sg = Pred + (size_t)b * 12288; }
    else                { W1 = wq;  W2 = wk;  Sg = Sred + (size_t)b * 4096; }

    for (int i = tid; i < 4096; i += 256) {
        const int r = i >> 6, c = i & 63;
        Wl[r * 65 + c] = W1[i];
        Sl[r * 65 + c] = Sg[i];
    }
    __syncthreads();

    const int rt = tid >> 4, ct = tid & 15;
    float acc[16];
#pragma unroll
    for (int i = 0; i < 16; ++i) acc[i] = 0.f;
    for (int cc = 0; cc < 64; ++cc) {
        float wr[4], sc[4];
#pragma unroll
        for (int j = 0; j < 4; ++j) {
            wr[j] = Wl[(rt * 4 + j) * 65 + cc];
            sc[j] = Sl[cc * 65 + ct * 4 + j];
        }
#pragma unroll
        for (int r = 0; r < 4; ++r)
#pragma unroll
            for (int c2 = 0; c2 < 4; ++c2)
                acc[r * 4 + c2] = fmaf(wr[r], sc[c2], acc[r * 4 + c2]);
    }
#pragma unroll
    for (int r = 0; r < 4; ++r)
#pragma unroll
        for (int c2 = 0; c2 < 4; ++c2)
            Tl[(rt * 4 + r) * 65 + ct * 4 + c2] = acc[r * 4 + c2];
    __syncthreads();
    for (int i = tid; i < 4096; i += 256) Sl[(i >> 6) * 65 + (i & 63)] = W2[i];
    __syncthreads();

    if (unit == 2) {
        for (int i = tid; i < 512; i += 256) {
            const int h = i >> 6, r = (i >> 3) & 7, d = i & 7;
            float s = 0.f;
#pragma unroll
            for (int c = 0; c < 64; ++c)
                s = fmaf(Tl[(h * 8 + r) * 65 + c], Sl[(h * 8 + d) * 65 + c], s);
            Gg[b * 512 + i] = s;
        }
    } else {
        const int r = tid >> 2, part = tid & 3;
        float s = 0.f;
#pragma unroll
        for (int q = 0; q < 16; ++q) {
            const int cp = part * 16 + q;
            s = fmaf(Tl[r * 65 + cp], Sl[r * 65 + cp], s);
        }
        red[tid] = s;
        __syncthreads();
        if (tid < 64) {
            const float v = red[tid * 4] + red[tid * 4 + 1] + red[tid * 4 + 2] + red[tid * 4 + 3];
            if (unit == 0)      nq2g[b * 64 + tid] = v;
            else if (unit == 1) nk2g[b * 64 + tid] = v;
            else                pooledg[b * 64 + tid] = v * (1.f / 65536.f);
        }
    }
}

// ================= K_B: MLP + softmax + tvl, grid 4 =================
__global__ __launch_bounds__(256) void dsattn_smallmid(
        const float* __restrict__ nq2g, const float* __restrict__ nk2g,
        const float* __restrict__ Gg, const float* __restrict__ pooledg,
        const float* __restrict__ temp, const float* __restrict__ w1,
        const float* __restrict__ w2, const float* __restrict__ wvl,
        float* __restrict__ hattg, float* __restrict__ tvlg) {
    __shared__ float att[512];
    __shared__ float z[16];
    const int b = blockIdx.x, tid = threadIdx.x;
    if (tid < 16) {
        float a = 0.f;
#pragma unroll
        for (int c = 0; c < 64; ++c) a = fmaf(w1[tid * 64 + c], pooledg[b * 64 + c], a);
        z[tid] = fmaxf(a, 0.f);
    }
    if (tid < 64) {
        const int h = tid >> 3;
        const float tpr = temp[h];
        const float nq = fmaxf(sqrtf(nq2g[b * 64 + tid]), 1e-12f);
        float a[8], m = -1e30f;
#pragma unroll
        for (int d = 0; d < 8; ++d) {
            const float nk = fmaxf(sqrtf(nk2g[b * 64 + h * 8 + d]), 1e-12f);
            a[d] = Gg[b * 512 + tid * 8 + d] / (nq * nk) * tpr;
            m = fmaxf(m, a[d]);
        }
        float ssum = 0.f;
#pragma unroll
        for (int d = 0; d < 8; ++d) { a[d] = expf(a[d] - m); ssum += a[d]; }
        const float inv = 1.f / ssum;
#pragma unroll
        for (int d = 0; d < 8; ++d) att[tid * 8 + d] = a[d] * inv;
    }
    __syncthreads();
    if (tid < 64) {
        float a = 0.f;
#pragma unroll
        for (int i = 0; i < 16; ++i) a = fmaf(w2[tid * 16 + i], z[i], a);
        hattg[b * 64 + tid] = tanhf(a);
    }
    for (int i = tid; i < 4096; i += 256) {
        const int m = i >> 6, c = i & 63, h = m >> 3;
        float s = 0.f;
#pragma unroll
        for (int d = 0; d < 8; ++d) s = fmaf(att[m * 8 + d], wvl[(h * 8 + d) * 64 + c], s);
        tvlg[b * 4096 + i] = s;
    }
}

// ================= K_C: fold -> At, Bt; grid (2 units, 4 img) =================
__global__ __launch_bounds__(256) void dsattn_fold(
        const float* __restrict__ wproj, const float* __restrict__ wvh,
        const float* __restrict__ hattg, const float* __restrict__ tvlg,
        float* __restrict__ At, float* __restrict__ Bt) {
    __shared__ float Pl[64 * 65];   // [o][m]
    __shared__ float Vl[64 * 65];   // [m][c]
    __shared__ float hm[64];
    const int unit = blockIdx.x, b = blockIdx.y, tid = threadIdx.x;
    if (tid < 64) hm[tid] = hattg[b * 64 + tid];
    for (int i = tid; i < 4096; i += 256) Pl[(i >> 6) * 65 + (i & 63)] = wproj[i];
    __syncthreads();
    for (int i = tid; i < 4096; i += 256) {
        const int m = i >> 6, c = i & 63;
        Vl[m * 65 + c] = (unit == 0) ? hm[m] * wvh[i] : tvlg[b * 4096 + i];
    }
    __syncthreads();

    const int rt = tid >> 4, ct = tid & 15;  // rt: c rows, ct: o cols
    float acc[16];
#pragma unroll
    for (int i = 0; i < 16; ++i) acc[i] = 0.f;
    for (int m = 0; m < 64; ++m) {
        float pv[4], vv[4];
#pragma unroll
        for (int j = 0; j < 4; ++j) {
            pv[j] = Pl[(ct * 4 + j) * 65 + m];
            vv[j] = Vl[m * 65 + rt * 4 + j];
        }
#pragma unroll
        for (int r = 0; r < 4; ++r)
#pragma unroll
            for (int c2 = 0; c2 < 4; ++c2)
                acc[r * 4 + c2] = fmaf(pv[c2], vv[r], acc[r * 4 + c2]);
    }
    float* outp = ((unit == 0) ? At : Bt) + (size_t)b * 4096;
#pragma unroll
    for (int r = 0; r < 4; ++r)
#pragma unroll
        for (int c2 = 0; c2 < 4; ++c2)
            outp[(rt * 4 + r) * 64 + ct * 4 + c2] = acc[r * 4 + c2];
}

// ================= K6: out = A_b @ xh + B_b @ y  (SGPR A/B, no LDS) =================
__global__ __launch_bounds__(256, 4) void dsattn_final(
        const float* __restrict__ xh, const float* __restrict__ y,
        const float* __restrict__ At, const float* __restrict__ Bt,
        float* __restrict__ out) {
    const int tid = threadIdx.x;
    const int b = blockIdx.y;
    const int lane = tid & 63;
    const int oc0 = __builtin_amdgcn_readfirstlane((tid >> 6) * 16);  // wave-uniform
    const size_t base = (size_t)b * IMGST + (size_t)blockIdx.x * 256 + lane * 4;
    const float* __restrict__ Ab = At + b * 4096 + oc0;
    const float* __restrict__ Bb = Bt + b * 4096 + oc0;

    float acc[16][4];
#pragma unroll
    for (int j = 0; j < 16; ++j)
#pragma unroll
        for (int k = 0; k < 4; ++k) acc[j][k] = 0.f;

#pragma unroll 2
    for (int c = 0; c < 64; ++c) {
        const float4 xv = *reinterpret_cast<const float4*>(xh + base + (size_t)c * NPX);
        const float4 yv = *reinterpret_cast<const float4*>(y  + base + (size_t)c * NPX);
#pragma unroll
        for (int j = 0; j < 16; ++j) {
            const float a  = Ab[c * 64 + j];   // uniform -> s_load
            const float bb = Bb[c * 64 + j];   // uniform -> s_load
            acc[j][0] = fmaf(a, xv.x, acc[j][0]);
            acc[j][1] = fmaf(a, xv.y, acc[j][1]);
            acc[j][2] = fmaf(a, xv.z, acc[j][2]);
            acc[j][3] = fmaf(a, xv.w, acc[j][3]);
            acc[j][0] = fmaf(bb, yv.x, acc[j][0]);
            acc[j][1] = fmaf(bb, yv.y, acc[j][1]);
            acc[j][2] = fmaf(bb, yv.z, acc[j][2]);
            acc[j][3] = fmaf(bb, yv.w, acc[j][3]);
        }
    }

    float* op = out + base;
#pragma unroll
    for (int j = 0; j < 16; ++j) {
        float4 v;
        v.x = acc[j][0]; v.y = acc[j][1]; v.z = acc[j][2]; v.w = acc[j][3];
        *reinterpret_cast<float4*>(op + (size_t)(oc0 + j) * NPX) = v;
    }
}

// ================= launch =================
extern "C" void kernel_launch(void* const* d_in, const int* in_sizes, int n_in,
                              void* d_out, int out_size, void* d_ws, size_t ws_size,
                              hipStream_t stream) {
    const float* x      = (const float*)d_in[0];
    const float* y      = (const float*)d_in[1];
    const float* hp1_w3 = (const float*)d_in[2];
    const float* hp1_w5 = (const float*)d_in[3];
    const float* hp1_w7 = (const float*)d_in[4];
    const float* hp2_w3 = (const float*)d_in[5];
    const float* hp2_w5 = (const float*)d_in[6];
    const float* hp2_w7 = (const float*)d_in[7];
    const float* qh_w   = (const float*)d_in[8];
    const float* kh_w   = (const float*)d_in[9];
    const float* vh_w   = (const float*)d_in[10];
    const float* ql_w   = (const float*)d_in[11];
    const float* kl_w   = (const float*)d_in[12];
    const float* vl_w   = (const float*)d_in[13];
    const float* proj_w = (const float*)d_in[14];
    const float* attn_w1 = (const float*)d_in[15];
    const float* attn_w2 = (const float*)d_in[16];
    const float* temperature = (const float*)d_in[17];

    float* out = (float*)d_out;

    // ws layout (floats); capacity >= 109.5 MB proven in round 15.
    float* xh     = (float*)d_ws;                    // 16,777,216
    float* Spart  = xh + (size_t)NB * IMGST;         // 2,097,152
    float* Sred   = Spart + (size_t)4 * 128 * 4096;  // 16,384
    float* Pred   = Sred + 16384;                    // 49,152
    float* nq2    = Pred + 49152;                    // 256
    float* nk2    = nq2 + 256;                       // 256
    float* G      = nk2 + 256;                       // 2,048
    float* pooled = G + 2048;                        // 256
    float* hatt   = pooled + 256;                    // 256
    float* tvl    = hatt + 256;                      // 16,384
    float* At     = tvl + 16384;                     // 16,384
    float* Bt     = At + 16384;                      // 16,384
    float* Ppart  = Bt + 16384;                      // 6,291,456 (ends ~101 MB)

    float* yh = out;   // d_out scratch: written by dwconv, read by grams,
                       // overwritten only by dsattn_final at the end.

    dsattn_dwconv2<<<dim3(1280, 8), 256, 0, stream>>>(x, y, xh, yh,
                                                      hp1_w3, hp1_w5, hp1_w7,
                                                      hp2_w3, hp2_w5, hp2_w7);
    dsattn_grams<<<dim3(256, 4), 256, 0, stream>>>(x, y, xh, yh, Spart, Ppart);
    dsattn_reduceSP<<<dim3(64, 4), 256, 0, stream>>>(Spart, Sred, Ppart, Pred);
    dsattn_sandwich<<<dim3(4, 4), 256, 0, stream>>>(Pred, Sred, ql_w, kl_w, qh_w, kh_w,
                                                    nq2, nk2, G, pooled);
    dsattn_smallmid<<<4, 256, 0, stream>>>(nq2, nk2, G, pooled, temperature,
                                           attn_w1, attn_w2, vl_w, hatt, tvl);
    dsattn_fold<<<dim3(2, 4), 256, 0, stream>>>(proj_w, vh_w, hatt, tvl, At, Bt);
    dsattn_final<<<dim3(256, 4), 256, 0, stream>>>(xh, y, At, Bt, out);
}

// Round 18
// 259.933 us; speedup vs baseline: 1.0259x; 1.0247x over previous
//
#include <hip/hip_runtime.h>
#include <hip/hip_bf16.h>
#include <math.h>

#define NPX   65536          // 256*256
#define IMGST 4194304        // 64*65536
#define NB    4
#define GP    68             // padded LDS row stride (16B-aligned float4 reads)

// ================= K1: depthwise conv (round-14 version, standalone) =========
template<int K, int RT>
__device__ __forceinline__ void dw_strip(const float* __restrict__ in,
                                         const float* __restrict__ wp,
                                         float* __restrict__ outp,
                                         int rowS, int c4) {
    float w[K * K];
#pragma unroll
    for (int i = 0; i < K * K; ++i) w[i] = wp[i];   // block-uniform -> s_load

    float acc[RT][4];
#pragma unroll
    for (int i = 0; i < RT; ++i)
#pragma unroll
        for (int j = 0; j < 4; ++j) acc[i][j] = 0.f;

    const bool lok = (c4 != 0);
    const bool rok = (c4 < 252);
    const int off0 = lok ? -4 : 0;
    const int off2 = rok ? 4 : 0;

#pragma unroll
    for (int ri = 0; ri < RT + K - 1; ++ri) {
        const int gr = rowS - K / 2 + ri;   // wave-uniform row index
        float v[12];
        if ((unsigned)gr < 256u) {
            const float* rp = in + gr * 256 + c4;
            const float4 m0 = *reinterpret_cast<const float4*>(rp + off0);
            const float4 m1 = *reinterpret_cast<const float4*>(rp);
            const float4 m2 = *reinterpret_cast<const float4*>(rp + off2);
            v[0] = lok ? m0.x : 0.f; v[1] = lok ? m0.y : 0.f;
            v[2] = lok ? m0.z : 0.f; v[3] = lok ? m0.w : 0.f;
            v[4] = m1.x; v[5] = m1.y; v[6] = m1.z; v[7] = m1.w;
            v[8] = rok ? m2.x : 0.f;  v[9] = rok ? m2.y : 0.f;
            v[10] = rok ? m2.z : 0.f; v[11] = rok ? m2.w : 0.f;
        } else {
#pragma unroll
            for (int t = 0; t < 12; ++t) v[t] = 0.f;
        }
#pragma unroll
        for (int i = 0; i < RT; ++i) {
            const int dy = ri - i;
            if (dy >= 0 && dy < K) {
#pragma unroll
                for (int dx = 0; dx < K; ++dx) {
                    const float wv = w[dy * K + dx];
#pragma unroll
                    for (int j = 0; j < 4; ++j)
                        acc[i][j] = fmaf(wv, v[j + dx + 4 - K / 2], acc[i][j]);
                }
            }
        }
    }

    float* obase = outp + (size_t)rowS * 256 + c4;
#pragma unroll
    for (int i = 0; i < RT; ++i) {
        float4 o;
        o.x = acc[i][0]; o.y = acc[i][1]; o.z = acc[i][2]; o.w = acc[i][3];
        *reinterpret_cast<float4*>(obase + i * 256) = o;
    }
}

__global__ __launch_bounds__(256) void dsattn_dwconv2(
        const float* __restrict__ xin, const float* __restrict__ yin,
        float* __restrict__ xout, float* __restrict__ yout,
        const float* __restrict__ x3, const float* __restrict__ x5,
        const float* __restrict__ x7, const float* __restrict__ y3,
        const float* __restrict__ y5, const float* __restrict__ y7) {
    const int tid = threadIdx.x;
    const int xcd = blockIdx.x & 7;
    const int v   = blockIdx.x >> 3;
    const int sel = blockIdx.y >> 2;
    const int b   = blockIdx.y & 3;
    const int tc = tid & 63, tr = tid >> 6;   // wave-uniform tr
    const int c4 = tc * 4;

    const float* inb = (sel == 0 ? xin : yin) + (size_t)b * IMGST;
    float* outb      = (sel == 0 ? xout : yout) + (size_t)b * IMGST;

    if (v < 64) {                 // k7 (longest) first
        const int idx = xcd * 64 + v;
        const int c = 48 + (idx >> 5), band = idx & 31;
        const float* w = (sel == 0 ? x7 : y7) + (c - 48) * 49;
        dw_strip<7, 2>(inb + (size_t)c * NPX, w, outb + (size_t)c * NPX,
                       band * 8 + tr * 2, c4);
    } else if (v < 128) {         // k3
        const int idx = xcd * 64 + (v - 64);
        const int c = idx >> 4, band = idx & 15;
        const float* w = (sel == 0 ? x3 : y3) + c * 9;
        dw_strip<3, 4>(inb + (size_t)c * NPX, w, outb + (size_t)c * NPX,
                       band * 16 + tr * 4, c4);
    } else {                      // k5
        const int idx = xcd * 32 + (v - 128);
        const int c = 32 + (idx >> 4), band = idx & 15;
        const float* w = (sel == 0 ? x5 : y5) + (c - 32) * 25;
        dw_strip<5, 4>(inb + (size_t)c * NPX, w, outb + (size_t)c * NPX,
                       band * 16 + tr * 4, c4);
    }
}

// ================= K2: cross-Gram, b128 LDS reads (stride GP=68) =================
__global__ __launch_bounds__(256) void dsattn_crossgram(
        const float* __restrict__ xh, const float* __restrict__ yh,
        float* __restrict__ Spart) {
    __shared__ __align__(16) float sx[64 * GP];
    __shared__ __align__(16) float sy[64 * GP];
    const int tid = threadIdx.x;
    const int chunk = blockIdx.x;
    const int b = blockIdx.y;
    const int rt = tid >> 4;      // 0..15
    const int ct = tid & 15;      // 0..15
    float acc[16];
#pragma unroll
    for (int i = 0; i < 16; ++i) acc[i] = 0.f;
    const size_t ibase = (size_t)b * IMGST + chunk * 512;

    for (int tile = 0; tile < 8; ++tile) {
        __syncthreads();
        for (int idx = tid; idx < 1024; idx += 256) {
            const int c = idx >> 4, p4 = (idx & 15) * 4;
            const size_t g = ibase + (size_t)c * NPX + tile * 64 + p4;
            const float4 vx = *reinterpret_cast<const float4*>(&xh[g]);
            const float4 vy = *reinterpret_cast<const float4*>(&yh[g]);
            sx[(p4 + 0) * GP + c] = vx.x; sx[(p4 + 1) * GP + c] = vx.y;
            sx[(p4 + 2) * GP + c] = vx.z; sx[(p4 + 3) * GP + c] = vx.w;
            sy[(p4 + 0) * GP + c] = vy.x; sy[(p4 + 1) * GP + c] = vy.y;
            sy[(p4 + 2) * GP + c] = vy.z; sy[(p4 + 3) * GP + c] = vy.w;
        }
        __syncthreads();
        for (int p = 0; p < 64; ++p) {
            const float4 xr = *reinterpret_cast<const float4*>(&sx[p * GP + rt * 4]);
            const float4 yc = *reinterpret_cast<const float4*>(&sy[p * GP + ct * 4]);
            acc[0]  = fmaf(xr.x, yc.x, acc[0]);  acc[1]  = fmaf(xr.x, yc.y, acc[1]);
            acc[2]  = fmaf(xr.x, yc.z, acc[2]);  acc[3]  = fmaf(xr.x, yc.w, acc[3]);
            acc[4]  = fmaf(xr.y, yc.x, acc[4]);  acc[5]  = fmaf(xr.y, yc.y, acc[5]);
            acc[6]  = fmaf(xr.y, yc.z, acc[6]);  acc[7]  = fmaf(xr.y, yc.w, acc[7]);
            acc[8]  = fmaf(xr.z, yc.x, acc[8]);  acc[9]  = fmaf(xr.z, yc.y, acc[9]);
            acc[10] = fmaf(xr.z, yc.z, acc[10]); acc[11] = fmaf(xr.z, yc.w, acc[11]);
            acc[12] = fmaf(xr.w, yc.x, acc[12]); acc[13] = fmaf(xr.w, yc.y, acc[13]);
            acc[14] = fmaf(xr.w, yc.z, acc[14]); acc[15] = fmaf(xr.w, yc.w, acc[15]);
        }
    }
    float* outp = Spart + ((size_t)b * 128 + chunk) * 4096;
#pragma unroll
    for (int r = 0; r < 4; ++r)
#pragma unroll
        for (int c2 = 0; c2 < 4; ++c2)
            outp[(rt * 4 + r) * 64 + ct * 4 + c2] = acc[r * 4 + c2];
}

// ================= K4: pooled Grams, b128 LDS reads (stride GP=68) ==============
__global__ __launch_bounds__(256) void dsattn_poolgram(
        const float* __restrict__ x, const float* __restrict__ y,
        float* __restrict__ Ppart) {
    __shared__ __align__(16) float sx[64 * GP];
    __shared__ __align__(16) float sy[64 * GP];
    const int tid = threadIdx.x;
    const int irow = blockIdx.x;   // pooled row
    const int b = blockIdx.y;
    const int rt = tid >> 4, ct = tid & 15;
    float aXY[16], aXX[16], aYY[16];
#pragma unroll
    for (int i = 0; i < 16; ++i) { aXY[i] = 0.f; aXX[i] = 0.f; aYY[i] = 0.f; }
    const size_t ibase = (size_t)b * IMGST + (size_t)(2 * irow) * 256;

    for (int tile = 0; tile < 2; ++tile) {
        __syncthreads();
        for (int idx = tid; idx < 4096; idx += 256) {
            const int c = idx >> 6, jj = idx & 63;
            const size_t g = ibase + (size_t)c * NPX + 2 * (tile * 64 + jj);
            const float2 a0 = *reinterpret_cast<const float2*>(x + g);
            const float2 a1 = *reinterpret_cast<const float2*>(x + g + 256);
            const float2 b0 = *reinterpret_cast<const float2*>(y + g);
            const float2 b1 = *reinterpret_cast<const float2*>(y + g + 256);
            sx[jj * GP + c] = 0.25f * (a0.x + a0.y + a1.x + a1.y);
            sy[jj * GP + c] = 0.25f * (b0.x + b0.y + b1.x + b1.y);
        }
        __syncthreads();
        for (int p = 0; p < 64; ++p) {
            const float4 xr = *reinterpret_cast<const float4*>(&sx[p * GP + rt * 4]);
            const float4 xc = *reinterpret_cast<const float4*>(&sx[p * GP + ct * 4]);
            const float4 yr = *reinterpret_cast<const float4*>(&sy[p * GP + rt * 4]);
            const float4 yc = *reinterpret_cast<const float4*>(&sy[p * GP + ct * 4]);
            const float xrv[4] = {xr.x, xr.y, xr.z, xr.w};
            const float xcv[4] = {xc.x, xc.y, xc.z, xc.w};
            const float yrv[4] = {yr.x, yr.y, yr.z, yr.w};
            const float ycv[4] = {yc.x, yc.y, yc.z, yc.w};
#pragma unroll
            for (int r = 0; r < 4; ++r)
#pragma unroll
                for (int c2 = 0; c2 < 4; ++c2) {
                    aXY[r * 4 + c2] = fmaf(xrv[r], ycv[c2], aXY[r * 4 + c2]);
                    aXX[r * 4 + c2] = fmaf(xrv[r], xcv[c2], aXX[r * 4 + c2]);
                    aYY[r * 4 + c2] = fmaf(yrv[r], ycv[c2], aYY[r * 4 + c2]);
                }
        }
    }
    float* outp = Ppart + ((size_t)b * 128 + irow) * 12288;
#pragma unroll
    for (int r = 0; r < 4; ++r)
#pragma unroll
        for (int c2 = 0; c2 < 4; ++c2) {
            const int o = (rt * 4 + r) * 64 + ct * 4 + c2;
            outp[o]        = aXY[r * 4 + c2];
            outp[4096 + o] = aXX[r * 4 + c2];
            outp[8192 + o] = aYY[r * 4 + c2];
        }
}

// ================= K2b: merged reduce (Spart -> Sred, Ppart -> Pred) ==========
__global__ __launch_bounds__(256) void dsattn_reduceSP(
        const float* __restrict__ Spart, float* __restrict__ Sred,
        const float* __restrict__ Ppart, float* __restrict__ Pred) {
    const int b = blockIdx.y;
    if (blockIdx.x < 16) {
        const int i = blockIdx.x * 256 + threadIdx.x;
        const float* p = Spart + (size_t)b * 128 * 4096 + i;
        float s = 0.f;
#pragma unroll 4
        for (int k = 0; k < 128; ++k) s += p[(size_t)k * 4096];
        Sred[b * 4096 + i] = s;
    } else {
        const int i = (blockIdx.x - 16) * 256 + threadIdx.x;
        const float* p = Ppart + (size_t)b * 128 * 12288 + i;
        float s = 0.f;
#pragma unroll 4
        for (int k = 0; k < 128; ++k) s += p[(size_t)k * 12288];
        Pred[b * 12288 + i] = s;
    }
}

// ================= K_A: sandwich products, grid (4 units, 4 img) =================
__global__ __launch_bounds__(256) void dsattn_sandwich(
        const float* __restrict__ Pred, const float* __restrict__ Sred,
        const float* __restrict__ wql, const float* __restrict__ wkl,
        const float* __restrict__ wq,  const float* __restrict__ wk,
        float* __restrict__ nq2g, float* __restrict__ nk2g,
        float* __restrict__ Gg, float* __restrict__ pooledg) {
    __shared__ float Wl[64 * 65];
    __shared__ float Sl[64 * 65];
    __shared__ float Tl[64 * 65];
    __shared__ float red[256];
    const int unit = blockIdx.x, b = blockIdx.y, tid = threadIdx.x;
    const float *W1, *W2, *Sg;
    if (unit == 0)      { W1 = wql; W2 = wql; Sg = Pred + (size_t)b * 12288 + 4096; }
    else if (unit == 1) { W1 = wkl; W2 = wkl; Sg = Pred + (size_t)b * 12288 + 8192; }
    else if (unit == 2) { W1 = wql; W2 = wkl; Sg = Pred + (size_t)b * 12288; }
    else                { W1 = wq;  W2 = wk;  Sg = Sred + (size_t)b * 4096; }

    for (int i = tid; i < 4096; i += 256) {
        const int r = i >> 6, c = i & 63;
        Wl[r * 65 + c] = W1[i];
        Sl[r * 65 + c] = Sg[i];
    }
    __syncthreads();

    const int rt = tid >> 4, ct = tid & 15;
    float acc[16];
#pragma unroll
    for (int i = 0; i < 16; ++i) acc[i] = 0.f;
    for (int cc = 0; cc < 64; ++cc) {
        float wr[4], sc[4];
#pragma unroll
        for (int j = 0; j < 4; ++j) {
            wr[j] = Wl[(rt * 4 + j) * 65 + cc];
            sc[j] = Sl[cc * 65 + ct * 4 + j];
        }
#pragma unroll
        for (int r = 0; r < 4; ++r)
#pragma unroll
            for (int c2 = 0; c2 < 4; ++c2)
                acc[r * 4 + c2] = fmaf(wr[r], sc[c2], acc[r * 4 + c2]);
    }
#pragma unroll
    for (int r = 0; r < 4; ++r)
#pragma unroll
        for (int c2 = 0; c2 < 4; ++c2)
            Tl[(rt * 4 + r) * 65 + ct * 4 + c2] = acc[r * 4 + c2];
    __syncthreads();
    for (int i = tid; i < 4096; i += 256) Sl[(i >> 6) * 65 + (i & 63)] = W2[i];
    __syncthreads();

    if (unit == 2) {
        for (int i = tid; i < 512; i += 256) {
            const int h = i >> 6, r = (i >> 3) & 7, d = i & 7;
            float s = 0.f;
#pragma unroll
            for (int c = 0; c < 64; ++c)
                s = fmaf(Tl[(h * 8 + r) * 65 + c], Sl[(h * 8 + d) * 65 + c], s);
            Gg[b * 512 + i] = s;
        }
    } else {
        const int r = tid >> 2, part = tid & 3;
        float s = 0.f;
#pragma unroll
        for (int q = 0; q < 16; ++q) {
            const int cp = part * 16 + q;
            s = fmaf(Tl[r * 65 + cp], Sl[r * 65 + cp], s);
        }
        red[tid] = s;
        __syncthreads();
        if (tid < 64) {
            const float v = red[tid * 4] + red[tid * 4 + 1] + red[tid * 4 + 2] + red[tid * 4 + 3];
            if (unit == 0)      nq2g[b * 64 + tid] = v;
            else if (unit == 1) nk2g[b * 64 + tid] = v;
            else                pooledg[b * 64 + tid] = v * (1.f / 65536.f);
        }
    }
}

// ================= K_B: MLP + softmax + tvl, grid 4 =================
__global__ __launch_bounds__(256) void dsattn_smallmid(
        const float* __restrict__ nq2g, const float* __restrict__ nk2g,
        const float* __restrict__ Gg, const float* __restrict__ pooledg,
        const float* __restrict__ temp, const float* __restrict__ w1,
        const float* __restrict__ w2, const float* __restrict__ wvl,
        float* __restrict__ hattg, float* __restrict__ tvlg) {
    __shared__ float att[512];
    __shared__ float z[16];
    const int b = blockIdx.x, tid = threadIdx.x;
    if (tid < 16) {
        float a = 0.f;
#pragma unroll
        for (int c = 0; c < 64; ++c) a = fmaf(w1[tid * 64 + c], pooledg[b * 64 + c], a);
        z[tid] = fmaxf(a, 0.f);
    }
    if (tid < 64) {
        const int h = tid >> 3;
        const float tpr = temp[h];
        const float nq = fmaxf(sqrtf(nq2g[b * 64 + tid]), 1e-12f);
        float a[8], m = -1e30f;
#pragma unroll
        for (int d = 0; d < 8; ++d) {
            const float nk = fmaxf(sqrtf(nk2g[b * 64 + h * 8 + d]), 1e-12f);
            a[d] = Gg[b * 512 + tid * 8 + d] / (nq * nk) * tpr;
            m = fmaxf(m, a[d]);
        }
        float ssum = 0.f;
#pragma unroll
        for (int d = 0; d < 8; ++d) { a[d] = expf(a[d] - m); ssum += a[d]; }
        const float inv = 1.f / ssum;
#pragma unroll
        for (int d = 0; d < 8; ++d) att[tid * 8 + d] = a[d] * inv;
    }
    __syncthreads();
    if (tid < 64) {
        float a = 0.f;
#pragma unroll
        for (int i = 0; i < 16; ++i) a = fmaf(w2[tid * 16 + i], z[i], a);
        hattg[b * 64 + tid] = tanhf(a);
    }
    for (int i = tid; i < 4096; i += 256) {
        const int m = i >> 6, c = i & 63, h = m >> 3;
        float s = 0.f;
#pragma unroll
        for (int d = 0; d < 8; ++d) s = fmaf(att[m * 8 + d], wvl[(h * 8 + d) * 64 + c], s);
        tvlg[b * 4096 + i] = s;
    }
}

// ================= K_C: fold -> At, Bt; grid (2 units, 4 img) =================
__global__ __launch_bounds__(256) void dsattn_fold(
        const float* __restrict__ wproj, const float* __restrict__ wvh,
        const float* __restrict__ hattg, const float* __restrict__ tvlg,
        float* __restrict__ At, float* __restrict__ Bt) {
    __shared__ float Pl[64 * 65];   // [o][m]
    __shared__ float Vl[64 * 65];   // [m][c]
    __shared__ float hm[64];
    const int unit = blockIdx.x, b = blockIdx.y, tid = threadIdx.x;
    if (tid < 64) hm[tid] = hattg[b * 64 + tid];
    for (int i = tid; i < 4096; i += 256) Pl[(i >> 6) * 65 + (i & 63)] = wproj[i];
    __syncthreads();
    for (int i = tid; i < 4096; i += 256) {
        const int m = i >> 6, c = i & 63;
        Vl[m * 65 + c] = (unit == 0) ? hm[m] * wvh[i] : tvlg[b * 4096 + i];
    }
    __syncthreads();

    const int rt = tid >> 4, ct = tid & 15;  // rt: c rows, ct: o cols
    float acc[16];
#pragma unroll
    for (int i = 0; i < 16; ++i) acc[i] = 0.f;
    for (int m = 0; m < 64; ++m) {
        float pv[4], vv[4];
#pragma unroll
        for (int j = 0; j < 4; ++j) {
            pv[j] = Pl[(ct * 4 + j) * 65 + m];
            vv[j] = Vl[m * 65 + rt * 4 + j];
        }
#pragma unroll
        for (int r = 0; r < 4; ++r)
#pragma unroll
            for (int c2 = 0; c2 < 4; ++c2)
                acc[r * 4 + c2] = fmaf(pv[c2], vv[r], acc[r * 4 + c2]);
    }
    float* outp = ((unit == 0) ? At : Bt) + (size_t)b * 4096;
#pragma unroll
    for (int r = 0; r < 4; ++r)
#pragma unroll
        for (int c2 = 0; c2 < 4; ++c2)
            outp[(rt * 4 + r) * 64 + ct * 4 + c2] = acc[r * 4 + c2];
}

// ================= K6: out = A_b @ xh + B_b @ y  (SGPR A/B, no LDS) =================
__global__ __launch_bounds__(256, 4) void dsattn_final(
        const float* __restrict__ xh, const float* __restrict__ y,
        const float* __restrict__ At, const float* __restrict__ Bt,
        float* __restrict__ out) {
    const int tid = threadIdx.x;
    const int b = blockIdx.y;
    const int lane = tid & 63;
    const int oc0 = __builtin_amdgcn_readfirstlane((tid >> 6) * 16);  // wave-uniform
    const size_t base = (size_t)b * IMGST + (size_t)blockIdx.x * 256 + lane * 4;
    const float* __restrict__ Ab = At + b * 4096 + oc0;
    const float* __restrict__ Bb = Bt + b * 4096 + oc0;

    float acc[16][4];
#pragma unroll
    for (int j = 0; j < 16; ++j)
#pragma unroll
        for (int k = 0; k < 4; ++k) acc[j][k] = 0.f;

#pragma unroll 2
    for (int c = 0; c < 64; ++c) {
        const float4 xv = *reinterpret_cast<const float4*>(xh + base + (size_t)c * NPX);
        const float4 yv = *reinterpret_cast<const float4*>(y  + base + (size_t)c * NPX);
#pragma unroll
        for (int j = 0; j < 16; ++j) {
            const float a  = Ab[c * 64 + j];   // uniform -> s_load
            const float bb = Bb[c * 64 + j];   // uniform -> s_load
            acc[j][0] = fmaf(a, xv.x, acc[j][0]);
            acc[j][1] = fmaf(a, xv.y, acc[j][1]);
            acc[j][2] = fmaf(a, xv.z, acc[j][2]);
            acc[j][3] = fmaf(a, xv.w, acc[j][3]);
            acc[j][0] = fmaf(bb, yv.x, acc[j][0]);
            acc[j][1] = fmaf(bb, yv.y, acc[j][1]);
            acc[j][2] = fmaf(bb, yv.z, acc[j][2]);
            acc[j][3] = fmaf(bb, yv.w, acc[j][3]);
        }
    }

    float* op = out + base;
#pragma unroll
    for (int j = 0; j < 16; ++j) {
        float4 v;
        v.x = acc[j][0]; v.y = acc[j][1]; v.z = acc[j][2]; v.w = acc[j][3];
        *reinterpret_cast<float4*>(op + (size_t)(oc0 + j) * NPX) = v;
    }
}

// ================= launch =================
extern "C" void kernel_launch(void* const* d_in, const int* in_sizes, int n_in,
                              void* d_out, int out_size, void* d_ws, size_t ws_size,
                              hipStream_t stream) {
    const float* x      = (const float*)d_in[0];
    const float* y      = (const float*)d_in[1];
    const float* hp1_w3 = (const float*)d_in[2];
    const float* hp1_w5 = (const float*)d_in[3];
    const float* hp1_w7 = (const float*)d_in[4];
    const float* hp2_w3 = (const float*)d_in[5];
    const float* hp2_w5 = (const float*)d_in[6];
    const float* hp2_w7 = (const float*)d_in[7];
    const float* qh_w   = (const float*)d_in[8];
    const float* kh_w   = (const float*)d_in[9];
    const float* vh_w   = (const float*)d_in[10];
    const float* ql_w   = (const float*)d_in[11];
    const float* kl_w   = (const float*)d_in[12];
    const float* vl_w   = (const float*)d_in[13];
    const float* proj_w = (const float*)d_in[14];
    const float* attn_w1 = (const float*)d_in[15];
    const float* attn_w2 = (const float*)d_in[16];
    const float* temperature = (const float*)d_in[17];

    float* out = (float*)d_out;

    // ws layout (floats); capacity >= 109.5 MB proven in round 15.
    float* xh     = (float*)d_ws;                    // 16,777,216
    float* Spart  = xh + (size_t)NB * IMGST;         // 2,097,152
    float* Sred   = Spart + (size_t)4 * 128 * 4096;  // 16,384
    float* Pred   = Sred + 16384;                    // 49,152
    float* nq2    = Pred + 49152;                    // 256
    float* nk2    = nq2 + 256;                       // 256
    float* G      = nk2 + 256;                       // 2,048
    float* pooled = G + 2048;                        // 256
    float* hatt   = pooled + 256;                    // 256
    float* tvl    = hatt + 256;                      // 16,384
    float* At     = tvl + 16384;                     // 16,384
    float* Bt     = At + 16384;                      // 16,384
    float* Ppart  = Bt + 16384;                      // 6,291,456 (ends ~101 MB)

    float* yh = out;   // d_out scratch: written by dwconv, read by crossgram,
                       // overwritten only by dsattn_final at the end.

    dsattn_dwconv2<<<dim3(1280, 8), 256, 0, stream>>>(x, y, xh, yh,
                                                      hp1_w3, hp1_w5, hp1_w7,
                                                      hp2_w3, hp2_w5, hp2_w7);
    dsattn_crossgram<<<dim3(128, 4), 256, 0, stream>>>(xh, yh, Spart);
    dsattn_poolgram<<<dim3(128, 4), 256, 0, stream>>>(x, y, Ppart);
    dsattn_reduceSP<<<dim3(64, 4), 256, 0, stream>>>(Spart, Sred, Ppart, Pred);
    dsattn_sandwich<<<dim3(4, 4), 256, 0, stream>>>(Pred, Sred, ql_w, kl_w, qh_w, kh_w,
                                                    nq2, nk2, G, pooled);
    dsattn_smallmid<<<4, 256, 0, stream>>>(nq2, nk2, G, pooled, temperature,
                                           attn_w1, attn_w2, vl_w, hatt, tvl);
    dsattn_fold<<<dim3(2, 4), 256, 0, stream>>>(proj_w, vh_w, hatt, tvl, At, Bt);
    dsattn_final<<<dim3(256, 4), 256, 0, stream>>>(xh, y, At, Bt, out);
}

// Round 19
// 229.952 us; speedup vs baseline: 1.1596x; 1.1304x over previous
//
#include <hip/hip_runtime.h>
#include <hip/hip_bf16.h>
#include <math.h>

#define NPX   65536          // 256*256
#define IMGST 4194304        // 64*65536
#define NB    4
#define GP    68             // padded LDS row stride (16B-aligned float4 reads)

// ---- bf16 helpers (RNE pack, shift unpack) ----
__device__ __forceinline__ unsigned short f2bf(float f) {
    unsigned int u = __float_as_uint(f);
    u += 0x7FFFu + ((u >> 16) & 1u);
    return (unsigned short)(u >> 16);
}
__device__ __forceinline__ float bf2f(unsigned short h) {
    return __uint_as_float(((unsigned int)h) << 16);
}

// ================= K1: depthwise conv, bf16 output =================
template<int K, int RT>
__device__ __forceinline__ void dw_strip(const float* __restrict__ in,
                                         const float* __restrict__ wp,
                                         unsigned short* __restrict__ outp,
                                         int rowS, int c4) {
    float w[K * K];
#pragma unroll
    for (int i = 0; i < K * K; ++i) w[i] = wp[i];   // block-uniform -> s_load

    float acc[RT][4];
#pragma unroll
    for (int i = 0; i < RT; ++i)
#pragma unroll
        for (int j = 0; j < 4; ++j) acc[i][j] = 0.f;

    const bool lok = (c4 != 0);
    const bool rok = (c4 < 252);
    const int off0 = lok ? -4 : 0;
    const int off2 = rok ? 4 : 0;

#pragma unroll
    for (int ri = 0; ri < RT + K - 1; ++ri) {
        const int gr = rowS - K / 2 + ri;   // wave-uniform row index
        float v[12];
        if ((unsigned)gr < 256u) {
            const float* rp = in + gr * 256 + c4;
            const float4 m0 = *reinterpret_cast<const float4*>(rp + off0);
            const float4 m1 = *reinterpret_cast<const float4*>(rp);
            const float4 m2 = *reinterpret_cast<const float4*>(rp + off2);
            v[0] = lok ? m0.x : 0.f; v[1] = lok ? m0.y : 0.f;
            v[2] = lok ? m0.z : 0.f; v[3] = lok ? m0.w : 0.f;
            v[4] = m1.x; v[5] = m1.y; v[6] = m1.z; v[7] = m1.w;
            v[8] = rok ? m2.x : 0.f;  v[9] = rok ? m2.y : 0.f;
            v[10] = rok ? m2.z : 0.f; v[11] = rok ? m2.w : 0.f;
        } else {
#pragma unroll
            for (int t = 0; t < 12; ++t) v[t] = 0.f;
        }
#pragma unroll
        for (int i = 0; i < RT; ++i) {
            const int dy = ri - i;
            if (dy >= 0 && dy < K) {
#pragma unroll
                for (int dx = 0; dx < K; ++dx) {
                    const float wv = w[dy * K + dx];
#pragma unroll
                    for (int j = 0; j < 4; ++j)
                        acc[i][j] = fmaf(wv, v[j + dx + 4 - K / 2], acc[i][j]);
                }
            }
        }
    }

    unsigned short* obase = outp + (size_t)rowS * 256 + c4;
#pragma unroll
    for (int i = 0; i < RT; ++i) {
        ushort4 o;
        o.x = f2bf(acc[i][0]); o.y = f2bf(acc[i][1]);
        o.z = f2bf(acc[i][2]); o.w = f2bf(acc[i][3]);
        *reinterpret_cast<ushort4*>(obase + i * 256) = o;
    }
}

__global__ __launch_bounds__(256) void dsattn_dwconv2(
        const float* __restrict__ xin, const float* __restrict__ yin,
        unsigned short* __restrict__ xout, unsigned short* __restrict__ yout,
        const float* __restrict__ x3, const float* __restrict__ x5,
        const float* __restrict__ x7, const float* __restrict__ y3,
        const float* __restrict__ y5, const float* __restrict__ y7) {
    const int tid = threadIdx.x;
    const int xcd = blockIdx.x & 7;
    const int v   = blockIdx.x >> 3;
    const int sel = blockIdx.y >> 2;
    const int b   = blockIdx.y & 3;
    const int tc = tid & 63, tr = tid >> 6;   // wave-uniform tr
    const int c4 = tc * 4;

    const float* inb = (sel == 0 ? xin : yin) + (size_t)b * IMGST;
    unsigned short* outb = (sel == 0 ? xout : yout) + (size_t)b * IMGST;

    if (v < 64) {                 // k7 (longest) first
        const int idx = xcd * 64 + v;
        const int c = 48 + (idx >> 5), band = idx & 31;
        const float* w = (sel == 0 ? x7 : y7) + (c - 48) * 49;
        dw_strip<7, 2>(inb + (size_t)c * NPX, w, outb + (size_t)c * NPX,
                       band * 8 + tr * 2, c4);
    } else if (v < 128) {         // k3
        const int idx = xcd * 64 + (v - 64);
        const int c = idx >> 4, band = idx & 15;
        const float* w = (sel == 0 ? x3 : y3) + c * 9;
        dw_strip<3, 4>(inb + (size_t)c * NPX, w, outb + (size_t)c * NPX,
                       band * 16 + tr * 4, c4);
    } else {                      // k5
        const int idx = xcd * 32 + (v - 128);
        const int c = 32 + (idx >> 4), band = idx & 15;
        const float* w = (sel == 0 ? x5 : y5) + (c - 32) * 25;
        dw_strip<5, 4>(inb + (size_t)c * NPX, w, outb + (size_t)c * NPX,
                       band * 16 + tr * 4, c4);
    }
}

// ================= K2: cross-Gram (bf16 inputs), b128 LDS reads ================
__global__ __launch_bounds__(256) void dsattn_crossgram(
        const unsigned short* __restrict__ xh, const unsigned short* __restrict__ yh,
        float* __restrict__ Spart) {
    __shared__ __align__(16) float sx[64 * GP];
    __shared__ __align__(16) float sy[64 * GP];
    const int tid = threadIdx.x;
    const int chunk = blockIdx.x;
    const int b = blockIdx.y;
    const int rt = tid >> 4;      // 0..15
    const int ct = tid & 15;      // 0..15
    float acc[16];
#pragma unroll
    for (int i = 0; i < 16; ++i) acc[i] = 0.f;
    const size_t ibase = (size_t)b * IMGST + chunk * 512;

    for (int tile = 0; tile < 8; ++tile) {
        __syncthreads();
        for (int idx = tid; idx < 1024; idx += 256) {
            const int c = idx >> 4, p4 = (idx & 15) * 4;
            const size_t g = ibase + (size_t)c * NPX + tile * 64 + p4;
            const ushort4 vx = *reinterpret_cast<const ushort4*>(&xh[g]);
            const ushort4 vy = *reinterpret_cast<const ushort4*>(&yh[g]);
            sx[(p4 + 0) * GP + c] = bf2f(vx.x); sx[(p4 + 1) * GP + c] = bf2f(vx.y);
            sx[(p4 + 2) * GP + c] = bf2f(vx.z); sx[(p4 + 3) * GP + c] = bf2f(vx.w);
            sy[(p4 + 0) * GP + c] = bf2f(vy.x); sy[(p4 + 1) * GP + c] = bf2f(vy.y);
            sy[(p4 + 2) * GP + c] = bf2f(vy.z); sy[(p4 + 3) * GP + c] = bf2f(vy.w);
        }
        __syncthreads();
        for (int p = 0; p < 64; ++p) {
            const float4 xr = *reinterpret_cast<const float4*>(&sx[p * GP + rt * 4]);
            const float4 yc = *reinterpret_cast<const float4*>(&sy[p * GP + ct * 4]);
            acc[0]  = fmaf(xr.x, yc.x, acc[0]);  acc[1]  = fmaf(xr.x, yc.y, acc[1]);
            acc[2]  = fmaf(xr.x, yc.z, acc[2]);  acc[3]  = fmaf(xr.x, yc.w, acc[3]);
            acc[4]  = fmaf(xr.y, yc.x, acc[4]);  acc[5]  = fmaf(xr.y, yc.y, acc[5]);
            acc[6]  = fmaf(xr.y, yc.z, acc[6]);  acc[7]  = fmaf(xr.y, yc.w, acc[7]);
            acc[8]  = fmaf(xr.z, yc.x, acc[8]);  acc[9]  = fmaf(xr.z, yc.y, acc[9]);
            acc[10] = fmaf(xr.z, yc.z, acc[10]); acc[11] = fmaf(xr.z, yc.w, acc[11]);
            acc[12] = fmaf(xr.w, yc.x, acc[12]); acc[13] = fmaf(xr.w, yc.y, acc[13]);
            acc[14] = fmaf(xr.w, yc.z, acc[14]); acc[15] = fmaf(xr.w, yc.w, acc[15]);
        }
    }
    float* outp = Spart + ((size_t)b * 128 + chunk) * 4096;
#pragma unroll
    for (int r = 0; r < 4; ++r)
#pragma unroll
        for (int c2 = 0; c2 < 4; ++c2)
            outp[(rt * 4 + r) * 64 + ct * 4 + c2] = acc[r * 4 + c2];
}

// ================= K4: pooled Grams (fp32 x,y), b128 LDS reads ================
__global__ __launch_bounds__(256) void dsattn_poolgram(
        const float* __restrict__ x, const float* __restrict__ y,
        float* __restrict__ Ppart) {
    __shared__ __align__(16) float sx[64 * GP];
    __shared__ __align__(16) float sy[64 * GP];
    const int tid = threadIdx.x;
    const int irow = blockIdx.x;   // pooled row
    const int b = blockIdx.y;
    const int rt = tid >> 4, ct = tid & 15;
    float aXY[16], aXX[16], aYY[16];
#pragma unroll
    for (int i = 0; i < 16; ++i) { aXY[i] = 0.f; aXX[i] = 0.f; aYY[i] = 0.f; }
    const size_t ibase = (size_t)b * IMGST + (size_t)(2 * irow) * 256;

    for (int tile = 0; tile < 2; ++tile) {
        __syncthreads();
        for (int idx = tid; idx < 4096; idx += 256) {
            const int c = idx >> 6, jj = idx & 63;
            const size_t g = ibase + (size_t)c * NPX + 2 * (tile * 64 + jj);
            const float2 a0 = *reinterpret_cast<const float2*>(x + g);
            const float2 a1 = *reinterpret_cast<const float2*>(x + g + 256);
            const float2 b0 = *reinterpret_cast<const float2*>(y + g);
            const float2 b1 = *reinterpret_cast<const float2*>(y + g + 256);
            sx[jj * GP + c] = 0.25f * (a0.x + a0.y + a1.x + a1.y);
            sy[jj * GP + c] = 0.25f * (b0.x + b0.y + b1.x + b1.y);
        }
        __syncthreads();
        for (int p = 0; p < 64; ++p) {
            const float4 xr = *reinterpret_cast<const float4*>(&sx[p * GP + rt * 4]);
            const float4 xc = *reinterpret_cast<const float4*>(&sx[p * GP + ct * 4]);
            const float4 yr = *reinterpret_cast<const float4*>(&sy[p * GP + rt * 4]);
            const float4 yc = *reinterpret_cast<const float4*>(&sy[p * GP + ct * 4]);
            const float xrv[4] = {xr.x, xr.y, xr.z, xr.w};
            const float xcv[4] = {xc.x, xc.y, xc.z, xc.w};
            const float yrv[4] = {yr.x, yr.y, yr.z, yr.w};
            const float ycv[4] = {yc.x, yc.y, yc.z, yc.w};
#pragma unroll
            for (int r = 0; r < 4; ++r)
#pragma unroll
                for (int c2 = 0; c2 < 4; ++c2) {
                    aXY[r * 4 + c2] = fmaf(xrv[r], ycv[c2], aXY[r * 4 + c2]);
                    aXX[r * 4 + c2] = fmaf(xrv[r], xcv[c2], aXX[r * 4 + c2]);
                    aYY[r * 4 + c2] = fmaf(yrv[r], ycv[c2], aYY[r * 4 + c2]);
                }
        }
    }
    float* outp = Ppart + ((size_t)b * 128 + irow) * 12288;
#pragma unroll
    for (int r = 0; r < 4; ++r)
#pragma unroll
        for (int c2 = 0; c2 < 4; ++c2) {
            const int o = (rt * 4 + r) * 64 + ct * 4 + c2;
            outp[o]        = aXY[r * 4 + c2];
            outp[4096 + o] = aXX[r * 4 + c2];
            outp[8192 + o] = aYY[r * 4 + c2];
        }
}

// ================= K2b: merged reduce (Spart -> Sred, Ppart -> Pred) ==========
__global__ __launch_bounds__(256) void dsattn_reduceSP(
        const float* __restrict__ Spart, float* __restrict__ Sred,
        const float* __restrict__ Ppart, float* __restrict__ Pred) {
    const int b = blockIdx.y;
    if (blockIdx.x < 16) {
        const int i = blockIdx.x * 256 + threadIdx.x;
        const float* p = Spart + (size_t)b * 128 * 4096 + i;
        float s = 0.f;
#pragma unroll 4
        for (int k = 0; k < 128; ++k) s += p[(size_t)k * 4096];
        Sred[b * 4096 + i] = s;
    } else {
        const int i = (blockIdx.x - 16) * 256 + threadIdx.x;
        const float* p = Ppart + (size_t)b * 128 * 12288 + i;
        float s = 0.f;
#pragma unroll 4
        for (int k = 0; k < 128; ++k) s += p[(size_t)k * 12288];
        Pred[b * 12288 + i] = s;
    }
}

// ================= K_A: sandwich products, grid (4 units, 4 img) =================
__global__ __launch_bounds__(256) void dsattn_sandwich(
        const float* __restrict__ Pred, const float* __restrict__ Sred,
        const float* __restrict__ wql, const float* __restrict__ wkl,
        const float* __restrict__ wq,  const float* __restrict__ wk,
        float* __restrict__ nq2g, float* __restrict__ nk2g,
        float* __restrict__ Gg, float* __restrict__ pooledg) {
    __shared__ float Wl[64 * 65];
    __shared__ float Sl[64 * 65];
    __shared__ float Tl[64 * 65];
    __shared__ float red[256];
    const int unit = blockIdx.x, b = blockIdx.y, tid = threadIdx.x;
    const float *W1, *W2, *Sg;
    if (unit == 0)      { W1 = wql; W2 = wql; Sg = Pred + (size_t)b * 12288 + 4096; }
    else if (unit == 1) { W1 = wkl; W2 = wkl; Sg = Pred + (size_t)b * 12288 + 8192; }
    else if (unit == 2) { W1 = wql; W2 = wkl; Sg = Pred + (size_t)b * 12288; }
    else                { W1 = wq;  W2 = wk;  Sg = Sred + (size_t)b * 4096; }

    for (int i = tid; i < 4096; i += 256) {
        const int r = i >> 6, c = i & 63;
        Wl[r * 65 + c] = W1[i];
        Sl[r * 65 + c] = Sg[i];
    }
    __syncthreads();

    const int rt = tid >> 4, ct = tid & 15;
    float acc[16];
#pragma unroll
    for (int i = 0; i < 16; ++i) acc[i] = 0.f;
    for (int cc = 0; cc < 64; ++cc) {
        float wr[4], sc[4];
#pragma unroll
        for (int j = 0; j < 4; ++j) {
            wr[j] = Wl[(rt * 4 + j) * 65 + cc];
            sc[j] = Sl[cc * 65 + ct * 4 + j];
        }
#pragma unroll
        for (int r = 0; r < 4; ++r)
#pragma unroll
            for (int c2 = 0; c2 < 4; ++c2)
                acc[r * 4 + c2] = fmaf(wr[r], sc[c2], acc[r * 4 + c2]);
    }
#pragma unroll
    for (int r = 0; r < 4; ++r)
#pragma unroll
        for (int c2 = 0; c2 < 4; ++c2)
            Tl[(rt * 4 + r) * 65 + ct * 4 + c2] = acc[r * 4 + c2];
    __syncthreads();
    for (int i = tid; i < 4096; i += 256) Sl[(i >> 6) * 65 + (i & 63)] = W2[i];
    __syncthreads();

    if (unit == 2) {
        for (int i = tid; i < 512; i += 256) {
            const int h = i >> 6, r = (i >> 3) & 7, d = i & 7;
            float s = 0.f;
#pragma unroll
            for (int c = 0; c < 64; ++c)
                s = fmaf(Tl[(h * 8 + r) * 65 + c], Sl[(h * 8 + d) * 65 + c], s);
            Gg[b * 512 + i] = s;
        }
    } else {
        const int r = tid >> 2, part = tid & 3;
        float s = 0.f;
#pragma unroll
        for (int q = 0; q < 16; ++q) {
            const int cp = part * 16 + q;
            s = fmaf(Tl[r * 65 + cp], Sl[r * 65 + cp], s);
        }
        red[tid] = s;
        __syncthreads();
        if (tid < 64) {
            const float v = red[tid * 4] + red[tid * 4 + 1] + red[tid * 4 + 2] + red[tid * 4 + 3];
            if (unit == 0)      nq2g[b * 64 + tid] = v;
            else if (unit == 1) nk2g[b * 64 + tid] = v;
            else                pooledg[b * 64 + tid] = v * (1.f / 65536.f);
        }
    }
}

// ================= K_B: MLP + softmax + tvl, grid 4 =================
__global__ __launch_bounds__(256) void dsattn_smallmid(
        const float* __restrict__ nq2g, const float* __restrict__ nk2g,
        const float* __restrict__ Gg, const float* __restrict__ pooledg,
        const float* __restrict__ temp, const float* __restrict__ w1,
        const float* __restrict__ w2, const float* __restrict__ wvl,
        float* __restrict__ hattg, float* __restrict__ tvlg) {
    __shared__ float att[512];
    __shared__ float z[16];
    const int b = blockIdx.x, tid = threadIdx.x;
    if (tid < 16) {
        float a = 0.f;
#pragma unroll
        for (int c = 0; c < 64; ++c) a = fmaf(w1[tid * 64 + c], pooledg[b * 64 + c], a);
        z[tid] = fmaxf(a, 0.f);
    }
    if (tid < 64) {
        const int h = tid >> 3;
        const float tpr = temp[h];
        const float nq = fmaxf(sqrtf(nq2g[b * 64 + tid]), 1e-12f);
        float a[8], m = -1e30f;
#pragma unroll
        for (int d = 0; d < 8; ++d) {
            const float nk = fmaxf(sqrtf(nk2g[b * 64 + h * 8 + d]), 1e-12f);
            a[d] = Gg[b * 512 + tid * 8 + d] / (nq * nk) * tpr;
            m = fmaxf(m, a[d]);
        }
        float ssum = 0.f;
#pragma unroll
        for (int d = 0; d < 8; ++d) { a[d] = expf(a[d] - m); ssum += a[d]; }
        const float inv = 1.f / ssum;
#pragma unroll
        for (int d = 0; d < 8; ++d) att[tid * 8 + d] = a[d] * inv;
    }
    __syncthreads();
    if (tid < 64) {
        float a = 0.f;
#pragma unroll
        for (int i = 0; i < 16; ++i) a = fmaf(w2[tid * 16 + i], z[i], a);
        hattg[b * 64 + tid] = tanhf(a);
    }
    for (int i = tid; i < 4096; i += 256) {
        const int m = i >> 6, c = i & 63, h = m >> 3;
        float s = 0.f;
#pragma unroll
        for (int d = 0; d < 8; ++d) s = fmaf(att[m * 8 + d], wvl[(h * 8 + d) * 64 + c], s);
        tvlg[b * 4096 + i] = s;
    }
}

// ================= K_C: fold -> At, Bt; grid (2 units, 4 img) =================
__global__ __launch_bounds__(256) void dsattn_fold(
        const float* __restrict__ wproj, const float* __restrict__ wvh,
        const float* __restrict__ hattg, const float* __restrict__ tvlg,
        float* __restrict__ At, float* __restrict__ Bt) {
    __shared__ float Pl[64 * 65];   // [o][m]
    __shared__ float Vl[64 * 65];   // [m][c]
    __shared__ float hm[64];
    const int unit = blockIdx.x, b = blockIdx.y, tid = threadIdx.x;
    if (tid < 64) hm[tid] = hattg[b * 64 + tid];
    for (int i = tid; i < 4096; i += 256) Pl[(i >> 6) * 65 + (i & 63)] = wproj[i];
    __syncthreads();
    for (int i = tid; i < 4096; i += 256) {
        const int m = i >> 6, c = i & 63;
        Vl[m * 65 + c] = (unit == 0) ? hm[m] * wvh[i] : tvlg[b * 4096 + i];
    }
    __syncthreads();

    const int rt = tid >> 4, ct = tid & 15;  // rt: c rows, ct: o cols
    float acc[16];
#pragma unroll
    for (int i = 0; i < 16; ++i) acc[i] = 0.f;
    for (int m = 0; m < 64; ++m) {
        float pv[4], vv[4];
#pragma unroll
        for (int j = 0; j < 4; ++j) {
            pv[j] = Pl[(ct * 4 + j) * 65 + m];
            vv[j] = Vl[m * 65 + rt * 4 + j];
        }
#pragma unroll
        for (int r = 0; r < 4; ++r)
#pragma unroll
            for (int c2 = 0; c2 < 4; ++c2)
                acc[r * 4 + c2] = fmaf(pv[c2], vv[r], acc[r * 4 + c2]);
    }
    float* outp = ((unit == 0) ? At : Bt) + (size_t)b * 4096;
#pragma unroll
    for (int r = 0; r < 4; ++r)
#pragma unroll
        for (int c2 = 0; c2 < 4; ++c2)
            outp[(rt * 4 + r) * 64 + ct * 4 + c2] = acc[r * 4 + c2];
}

// ================= K6: out = A_b @ xh(bf16) + B_b @ y  (SGPR A/B) ==============
__global__ __launch_bounds__(256, 4) void dsattn_final(
        const unsigned short* __restrict__ xh, const float* __restrict__ y,
        const float* __restrict__ At, const float* __restrict__ Bt,
        float* __restrict__ out) {
    const int tid = threadIdx.x;
    const int b = blockIdx.y;
    const int lane = tid & 63;
    const int oc0 = __builtin_amdgcn_readfirstlane((tid >> 6) * 16);  // wave-uniform
    const size_t base = (size_t)b * IMGST + (size_t)blockIdx.x * 256 + lane * 4;
    const float* __restrict__ Ab = At + b * 4096 + oc0;
    const float* __restrict__ Bb = Bt + b * 4096 + oc0;

    float acc[16][4];
#pragma unroll
    for (int j = 0; j < 16; ++j)
#pragma unroll
        for (int k = 0; k < 4; ++k) acc[j][k] = 0.f;

#pragma unroll 2
    for (int c = 0; c < 64; ++c) {
        const ushort4 xv4 = *reinterpret_cast<const ushort4*>(xh + base + (size_t)c * NPX);
        float4 xv;
        xv.x = bf2f(xv4.x); xv.y = bf2f(xv4.y); xv.z = bf2f(xv4.z); xv.w = bf2f(xv4.w);
        const float4 yv = *reinterpret_cast<const float4*>(y + base + (size_t)c * NPX);
#pragma unroll
        for (int j = 0; j < 16; ++j) {
            const float a  = Ab[c * 64 + j];   // uniform -> s_load
            const float bb = Bb[c * 64 + j];   // uniform -> s_load
            acc[j][0] = fmaf(a, xv.x, acc[j][0]);
            acc[j][1] = fmaf(a, xv.y, acc[j][1]);
            acc[j][2] = fmaf(a, xv.z, acc[j][2]);
            acc[j][3] = fmaf(a, xv.w, acc[j][3]);
            acc[j][0] = fmaf(bb, yv.x, acc[j][0]);
            acc[j][1] = fmaf(bb, yv.y, acc[j][1]);
            acc[j][2] = fmaf(bb, yv.z, acc[j][2]);
            acc[j][3] = fmaf(bb, yv.w, acc[j][3]);
        }
    }

    float* op = out + base;
#pragma unroll
    for (int j = 0; j < 16; ++j) {
        float4 v;
        v.x = acc[j][0]; v.y = acc[j][1]; v.z = acc[j][2]; v.w = acc[j][3];
        *reinterpret_cast<float4*>(op + (size_t)(oc0 + j) * NPX) = v;
    }
}

// ================= launch =================
extern "C" void kernel_launch(void* const* d_in, const int* in_sizes, int n_in,
                              void* d_out, int out_size, void* d_ws, size_t ws_size,
                              hipStream_t stream) {
    const float* x      = (const float*)d_in[0];
    const float* y      = (const float*)d_in[1];
    const float* hp1_w3 = (const float*)d_in[2];
    const float* hp1_w5 = (const float*)d_in[3];
    const float* hp1_w7 = (const float*)d_in[4];
    const float* hp2_w3 = (const float*)d_in[5];
    const float* hp2_w5 = (const float*)d_in[6];
    const float* hp2_w7 = (const float*)d_in[7];
    const float* qh_w   = (const float*)d_in[8];
    const float* kh_w   = (const float*)d_in[9];
    const float* vh_w   = (const float*)d_in[10];
    const float* ql_w   = (const float*)d_in[11];
    const float* kl_w   = (const float*)d_in[12];
    const float* vl_w   = (const float*)d_in[13];
    const float* proj_w = (const float*)d_in[14];
    const float* attn_w1 = (const float*)d_in[15];
    const float* attn_w2 = (const float*)d_in[16];
    const float* temperature = (const float*)d_in[17];

    float* out = (float*)d_out;

    // ws layout; capacity >= 109.5 MB proven in round 15.
    unsigned short* xh = (unsigned short*)d_ws;      // 16,777,216 bf16 = 33.5 MB
    float* base   = (float*)d_ws + 8388608;          // after xh
    float* Spart  = base;                            // 2,097,152
    float* Sred   = Spart + (size_t)4 * 128 * 4096;  // 16,384
    float* Pred   = Sred + 16384;                    // 49,152
    float* nq2    = Pred + 49152;                    // 256
    float* nk2    = nq2 + 256;                       // 256
    float* G      = nk2 + 256;                       // 2,048
    float* pooled = G + 2048;                        // 256
    float* hatt   = pooled + 256;                    // 256
    float* tvl    = hatt + 256;                      // 16,384
    float* At     = tvl + 16384;                     // 16,384
    float* Bt     = At + 16384;                      // 16,384
    float* Ppart  = Bt + 16384;                      // 6,291,456 (ends ~70 MB)

    unsigned short* yh = (unsigned short*)d_out;     // d_out scratch (33.5 of 67 MB):
                                                     // written by dwconv (bf16),
                                                     // read by crossgram, then fully
                                                     // overwritten by dsattn_final.

    dsattn_dwconv2<<<dim3(1280, 8), 256, 0, stream>>>(x, y, xh, yh,
                                                      hp1_w3, hp1_w5, hp1_w7,
                                                      hp2_w3, hp2_w5, hp2_w7);
    dsattn_crossgram<<<dim3(128, 4), 256, 0, stream>>>(xh, yh, Spart);
    dsattn_poolgram<<<dim3(128, 4), 256, 0, stream>>>(x, y, Ppart);
    dsattn_reduceSP<<<dim3(64, 4), 256, 0, stream>>>(Spart, Sred, Ppart, Pred);
    dsattn_sandwich<<<dim3(4, 4), 256, 0, stream>>>(Pred, Sred, ql_w, kl_w, qh_w, kh_w,
                                                    nq2, nk2, G, pooled);
    dsattn_smallmid<<<4, 256, 0, stream>>>(nq2, nk2, G, pooled, temperature,
                                           attn_w1, attn_w2, vl_w, hatt, tvl);
    dsattn_fold<<<dim3(2, 4), 256, 0, stream>>>(proj_w, vh_w, hatt, tvl, At, Bt);
    dsattn_final<<<dim3(256, 4), 256, 0, stream>>>(xh, y, At, Bt, out);
}